// Round 16
// baseline (802.445 us; speedup 1.0000x reference)
//
#include <hip/hip_runtime.h>

#define NTOK 2048
#define DIM  1024          // K elements; == bytes for fp8
#define OUTD 50257
#define OPAD 50304         // 393*128
#define NCB  393           // column blocks (128 wide)
#define SEGC 12            // slots per (row, colblock) segment
#define TOPK 32
#define RCAP 256           // refine capacity (determinism: nref<=RCAP always)
#define NREF 80            // exact-refine depth (8.9 sigma rank margin vs fp8 coarse noise)
#define THRESH 0.08f
#define NBLK 6288          // gemm grid: 16 M-tiles(128) x 393 col-blocks

typedef float f32x4  __attribute__((ext_vector_type(4)));
typedef float f32x16 __attribute__((ext_vector_type(16)));
typedef int   i32x4  __attribute__((ext_vector_type(4)));
typedef int   i32x8  __attribute__((ext_vector_type(8)));

// ---- f32 -> OCP e4m3fn, RNE, saturating (hand-rolled: no API risk) -------
__device__ __forceinline__ unsigned int f2e4m3(float f){
    unsigned int u = __float_as_uint(f);
    unsigned int sgn = (u >> 24) & 0x80u;
    int exp = (int)((u >> 23) & 0xFF);
    unsigned int man = u & 0x7FFFFF;
    int e = exp - 127;
    if (e >= 9) return sgn | 0x7E;                 // saturate to 448
    unsigned int full = 0x800000u | man;           // 24-bit significand
    int shift = (e >= -6) ? 20 : 20 + (-6 - e);    // subnormal extra shift
    if (shift >= 24) return sgn;                   // -> 0 (also f32 subnorm/0)
    unsigned int kept = full >> shift;
    unsigned int rem  = full & ((1u << shift) - 1);
    unsigned int half = 1u << (shift - 1);
    if (rem > half || (rem == half && (kept & 1))) kept++;
    if (e >= -6){
        unsigned int ee = (unsigned)(e + 7);
        if (kept >= 16){ kept >>= 1; ee++; }
        if (ee > 15 || (ee == 15 && (kept & 7) > 6)) return sgn | 0x7E;
        return sgn | (ee << 3) | (kept - 8);
    } else {
        if (kept >= 8) return sgn | 0x08;          // rounds up to min normal
        return sgn | kept;                         // subnormal
    }
}
__device__ __forceinline__ unsigned int pack4_e4m3(float a, float b, float c, float d){
    return f2e4m3(a) | (f2e4m3(b) << 8) | (f2e4m3(c) << 16) | (f2e4m3(d) << 24);
}

#define GLDS(gp, lp) __builtin_amdgcn_global_load_lds( \
    (__attribute__((address_space(1))) void*)(gp),     \
    (__attribute__((address_space(3))) void*)(lp), 16, 0, 0)

// ------- kernel 1: x-row L2-normalize, x8 = e4m3(32 * x_hat) --------------
extern "C" __global__ void k_init(const float* __restrict__ x,
                                  unsigned char* __restrict__ x8){
    __shared__ double ls[4];
    const int row = blockIdx.x, t = threadIdx.x;
    float4 v = ((const float4*)(x + (size_t)row * DIM))[t];
    double s = (double)v.x*v.x + (double)v.y*v.y
             + (double)v.z*v.z + (double)v.w*v.w;
    for (int d = 32; d >= 1; d >>= 1) s += __shfl_xor(s, d, 64);
    const int wv = t >> 6, ln = t & 63;
    if (ln == 0) ls[wv] = s;
    __syncthreads();
    double tot = ls[0] + ls[1] + ls[2] + ls[3];
    float sc = (float)(32.0 / fmax(sqrt(tot), 1e-12));
    ((unsigned int*)(x8 + (size_t)row * DIM))[t] =
        pack4_e4m3(v.x*sc, v.y*sc, v.z*sc, v.w*sc);
}

// ------- kernel 2: w8 = e4m3(32 * w_hat); ri64 = 1/max(||w||,eps) ---------
extern "C" __global__ void k_wnorm(const float* __restrict__ w,
                                   unsigned char* __restrict__ w8,
                                   double* __restrict__ ri64){
    __shared__ double ls[4];
    int r = blockIdx.x, t = threadIdx.x;
    if (r < OUTD){
        float4 v = ((const float4*)(w + (size_t)r * DIM))[t];
        double s = (double)v.x*v.x + (double)v.y*v.y
                 + (double)v.z*v.z + (double)v.w*v.w;
        for (int d = 32; d >= 1; d >>= 1) s += __shfl_xor(s, d, 64);
        int wv = t >> 6, ln = t & 63;
        if (ln == 0) ls[wv] = s;
        __syncthreads();
        double tot = ls[0] + ls[1] + ls[2] + ls[3];
        double ri = 1.0 / fmax(sqrt(tot), 1e-12);
        if (t == 0) ri64[r] = ri;
        float sc = (float)(32.0 * ri);
        ((unsigned int*)(w8 + (size_t)r * DIM))[t] =
            pack4_e4m3(v.x*sc, v.y*sc, v.z*sc, v.w*sc);
    } else { // pad rows: zero -> acc 0 -> filtered
        ((unsigned int*)(w8 + (size_t)r * DIM))[t] = 0u;
        if (t == 0) ri64[r] = 0.0;
    }
}

// ------ kernel 3: MX-fp8 MFMA GEMM (32x32x64 scaled, unit e8m0 scales) ----
// R10's verified-numerics kernel (absmax passed), de-spilled per rule #20:
// NAMED accumulators acc00..acc11 (f32x16 each), epilogue with compile-time
// vector subscripts only. 128x128 tile, BK=64, 4 waves 2x2 (64x64/wave),
// dbuf 32KB LDS, swizzle slot^((row>>1)&3) on BOTH source and read.
// Zeroing amortized: 2 float4 stores/iter for iters 0..7 (16 total) with
// counted vmcnt(2) barrier (4 GLDS older retire in order — m135; stores
// stay in flight). Compiler fence pins store-after-GLDS issue order.
#define RD32(base, R) ({ \
  i32x4 lo_ = *(const i32x4*)((base) + (R)*64 + ((( (kh<<1)    ) ^ (((R)>>1)&3))*16)); \
  i32x4 hi_ = *(const i32x4*)((base) + (R)*64 + ((( (kh<<1) + 1) ^ (((R)>>1)&3))*16)); \
  i32x8 v_; v_[0]=lo_[0]; v_[1]=lo_[1]; v_[2]=lo_[2]; v_[3]=lo_[3]; \
            v_[4]=hi_[0]; v_[5]=hi_[1]; v_[6]=hi_[2]; v_[7]=hi_[3]; v_; })

#define MXMFMA(A, B, C) __builtin_amdgcn_mfma_scale_f32_32x32x64_f8f6f4( \
    (A), (B), (C), 0, 0, 0, 0x7F7F7F7F, 0, 0x7F7F7F7F)

#define COMPUTE(b) do { \
  const char* Ab_ = As[b]; \
  const char* Bb_ = Bs[b]; \
  i32x8 a0_ = RD32(Ab_, wm*64      + lr32); \
  i32x8 a1_ = RD32(Ab_, wm*64 + 32 + lr32); \
  i32x8 b0_ = RD32(Bb_, wn*64      + lr32); \
  i32x8 b1_ = RD32(Bb_, wn*64 + 32 + lr32); \
  __builtin_amdgcn_s_setprio(1); \
  acc00 = MXMFMA(a0_, b0_, acc00); \
  acc01 = MXMFMA(a0_, b1_, acc01); \
  acc10 = MXMFMA(a1_, b0_, acc10); \
  acc11 = MXMFMA(a1_, b1_, acc11); \
  __builtin_amdgcn_s_setprio(0); \
} while(0)

#define STAGE(b, K0) do { \
  GLDS(x8 + offA0 + (K0), As[b] + tid*16); \
  GLDS(x8 + offA1 + (K0), As[b] + (tid+256)*16); \
  GLDS(w8 + offB0 + (K0), Bs[b] + tid*16); \
  GLDS(w8 + offB1 + (K0), Bs[b] + (tid+256)*16); \
} while(0)

#define VBARZ2() do { \
  asm volatile("s_waitcnt vmcnt(2)" ::: "memory"); \
  __builtin_amdgcn_s_barrier(); \
  asm volatile("" ::: "memory"); \
} while(0)

// epilogue per quadrant: compile-time-constant vector subscripts only
#define EPI(ACC, I, J) do { \
  int gcol_ = bn + wn*64 + (J)*32 + lr32; \
  bool ok_ = gcol_ < OUTD; \
  int base_ = wm*64 + (I)*32 + 4*kh; \
  _Pragma("unroll") \
  for (int g_ = 0; g_ < 16; ++g_){ \
    float sc_ = ACC[g_] * inv; \
    if (ok_ && sc_ > THRESH){ \
      int lrow_ = base_ + (g_ & 3) + 8*(g_ >> 2); \
      int pos_ = atomicAdd(&lcnt[lrow_], 1); \
      if (pos_ < SEGC) \
        cpk[((size_t)(bm + lrow_)*NCB + cb)*SEGC + pos_] = \
            ((unsigned long long)(unsigned)gcol_ << 32) | \
            (unsigned long long)__float_as_uint(sc_); \
    } \
  } \
} while(0)

extern "C" __global__ __launch_bounds__(256)
void k_gemm(const unsigned char* __restrict__ x8,
            const unsigned char* __restrict__ w8,
            unsigned long long* __restrict__ cpk,
            unsigned char* __restrict__ cnt8,
            float* __restrict__ out){
    __shared__ __align__(16) char As[2][8192];
    __shared__ __align__(16) char Bs[2][8192];
    __shared__ int lcnt[128];
    const int tid = threadIdx.x;

    // bijective chunked XCD remap: 6288 = 8*786
    const int orig  = blockIdx.x;
    const int newid = (orig & 7) * 786 + (orig >> 3);
    const int bm    = (newid & 15) * 128;
    const int cb    = newid >> 4;               // column block 0..392
    const int bn    = cb * 128;

    const int wv = tid >> 6, lane = tid & 63;
    const int wm = wv >> 1,  wn = wv & 1;       // 2x2 waves, 64x64 each
    const int lr32 = lane & 31, kh = lane >> 5;

    if (tid < 128) lcnt[tid] = 0;

    f32x16 acc00 = {0}, acc01 = {0}, acc10 = {0}, acc11 = {0};

    // staging: 512 16B segs per matrix per K-tile; 2 each (A,B)/thread.
    // seg -> row = seg>>2, phys slot = seg&3; SOURCE col pre-swizzled.
    // dst = seg*16: wave-contiguous (m104-safe: wave base + lane*16).
    const int r0 = tid >> 2,          s0 = tid & 3;
    const int r1 = (tid+256) >> 2;
    const int l0 = s0 ^ ((r0 >> 1) & 3);
    const int l1 = s0 ^ ((r1 >> 1) & 3);
    const size_t offA0 = (size_t)(bm + r0)*DIM + l0*16;
    const size_t offA1 = (size_t)(bm + r1)*DIM + l1*16;
    const size_t offB0 = (size_t)(bn + r0)*DIM + l0*16;
    const size_t offB1 = (size_t)(bn + r1)*DIM + l1*16;

    const size_t n4 = (size_t)NTOK * OUTD / 4;  // 25,731,584
    const float4 z4 = make_float4(0.f, 0.f, 0.f, 0.f);

    STAGE(0, 0);
    __syncthreads();                 // buf0 staged; lcnt init visible
    int buf = 0, it = 0;
    for (int k0 = 64; k0 < DIM; k0 += 64, ++it){
        STAGE(buf ^ 1, k0);          // prefetch next K-tile (4 GLDS)
        asm volatile("" ::: "memory");   // pin: stores issue after GLDS
        if (it < 8){                 // amortized zero: 2 float4/thread
            size_t zi0 = ((size_t)orig*16 + it*2)*256 + tid;
            size_t zi1 = zi0 + 256;
            if (zi0 >= n4) zi0 = n4 - 1;   // idempotent, keeps queue uniform
            if (zi1 >= n4) zi1 = n4 - 1;
            ((float4*)out)[zi0] = z4;
            ((float4*)out)[zi1] = z4;
        }
        COMPUTE(buf);                // 8 ds_read_b128 + 4 mfma_scale / wave
        if (it < 8) VBARZ2();        // counted: stores stay in flight
        else        __syncthreads();
        buf ^= 1;
    }
    COMPUTE(buf);

    // epilogue: cos = acc/1024; append to this block's (row, cb) segments
    const float inv = 1.0f / 1024.0f;
    EPI(acc00, 0, 0);
    EPI(acc01, 0, 1);
    EPI(acc10, 1, 0);
    EPI(acc11, 1, 1);
    __syncthreads();                 // drains cpk stores (few/thread) only
    if (tid < 128)
        cnt8[(size_t)(bm + tid)*NCB + cb] =
            (unsigned char)min(lcnt[tid], SEGC);
}

// -------- kernel 4: select + f64 refine + scatter (zeroing in gemm) -------
// Determinism: refine SET = {candidates in bins >= bstar} is order-invariant;
// segment contents are set-complete (cap-12 overflow prob ~3e-7/run);
// f64 scores + (score desc, idx asc) sort -> arrival-order independent.
extern "C" __global__ __launch_bounds__(256)
void k_sel(const float* __restrict__ x, const float* __restrict__ w,
           const float* __restrict__ bias,
           const unsigned long long* __restrict__ cpk,
           const unsigned char* __restrict__ cnt8,
           const double* __restrict__ ri64,
           float* __restrict__ out){
    const int row = blockIdx.x, tid = threadIdx.x;
    __shared__ float  xl[DIM];
    __shared__ int    hist[256];
    __shared__ int    bstar, nref;
    __shared__ int    ridx[RCAP];
    __shared__ double rsc[RCAP];
    __shared__ double rdv[RCAP];

    ((float4*)xl)[tid] = ((const float4*)(x + (size_t)row*DIM))[tid];
    hist[tid] = 0;
    if (tid == 0) nref = 0;
    __syncthreads();

    const unsigned char* rc8 = cnt8 + (size_t)row*NCB;
    const unsigned long long* rseg = cpk + (size_t)row*NCB*SEGC;

    // histogram of coarse scores (bins of 7.8e-4 over [0.08, 0.28])
    for (int cb = tid; cb < NCB; cb += 256){
        int c = rc8[cb];
        for (int j = 0; j < c; ++j){
            float s = __uint_as_float((unsigned)(rseg[cb*SEGC + j] & 0xFFFFFFFFu));
            int b = (int)((s - THRESH) * 1280.f);
            b = max(0, min(255, b));
            atomicAdd(&hist[b], 1);
        }
    }
    __syncthreads();
    if (tid == 0){  // smallest bin whose top-cumulative >= NREF
        int cum = 0, b = 255;
        for (; b >= 0; --b){ cum += hist[b]; if (cum >= NREF) break; }
        bstar = b < 0 ? 0 : b;
    }
    __syncthreads();
    const int bs_ = bstar;
    for (int cb = tid; cb < NCB; cb += 256){
        int c = rc8[cb];
        for (int j = 0; j < c; ++j){
            unsigned long long pk = rseg[cb*SEGC + j];
            float s = __uint_as_float((unsigned)(pk & 0xFFFFFFFFu));
            int b = (int)((s - THRESH) * 1280.f);
            b = max(0, min(255, b));
            if (b >= bs_){
                int p = atomicAdd(&nref, 1);
                if (p < RCAP) ridx[p] = (int)(pk >> 32);
            }
        }
    }
    __syncthreads();
    const int nr = min(nref, RCAP);

    // f64 refine: one wave per candidate, float4-vectorized loads
    const int wv = tid >> 6, lane = tid & 63;
    const float4* xl4 = (const float4*)xl;
    for (int q = wv; q < nr; q += 4){
        int col = ridx[q];
        const float4* wr4 = (const float4*)(w + (size_t)col*DIM);
        double s = 0.0;
        #pragma unroll
        for (int u = 0; u < 4; ++u){
            float4 a = xl4[lane + 64*u];
            float4 b = wr4[lane + 64*u];
            s = fma((double)a.x, (double)b.x, s);
            s = fma((double)a.y, (double)b.y, s);
            s = fma((double)a.z, (double)b.z, s);
            s = fma((double)a.w, (double)b.w, s);
        }
        for (int d = 32; d >= 1; d >>= 1) s += __shfl_xor(s, d, 64);
        if (lane == 0){ rdv[q] = s; rsc[q] = s * ri64[col]; }
    }
    __syncthreads();
    if (tid >= nr){ rsc[tid] = -1.0e300; ridx[tid] = 0x7FFFFFFF; rdv[tid] = 0.0; }
    __syncthreads();

    // bitonic sort 256: descending score, ties -> smaller index
    for (int k = 2; k <= RCAP; k <<= 1){
        for (int j = k >> 1; j > 0; j >>= 1){
            int i = tid, ixj = i ^ j;
            if (ixj > i){
                double sa = rsc[i], sb = rsc[ixj];
                int ia = ridx[i], ib = ridx[ixj];
                bool dir = ((i & k) == 0);
                bool pb = (sb > sa) || (sb == sa && ib < ia);
                if (pb == dir){
                    rsc[i] = sb; rsc[ixj] = sa;
                    ridx[i] = ib; ridx[ixj] = ia;
                    double t = rdv[i]; rdv[i] = rdv[ixj]; rdv[ixj] = t;
                }
            }
            __syncthreads();
        }
    }
    if (tid < TOPK && tid < nr){
        int col = ridx[tid];
        out[(size_t)row*OUTD + col] = (float)rdv[tid] + bias[col];
    }
}

// ---------------- launch --------------------------------------------------
extern "C" void kernel_launch(void* const* d_in, const int* in_sizes, int n_in,
                              void* d_out, int out_size, void* d_ws, size_t ws_size,
                              hipStream_t stream){
    const float* x    = (const float*)d_in[0];
    const float* wgt  = (const float*)d_in[1];
    const float* bias = (const float*)d_in[2];
    float* out = (float*)d_out;
    char* ws = (char*)d_ws;

    // workspace carve (~132 MB)
    unsigned char* w8 = (unsigned char*)ws;                         // 51,511,296
    unsigned char* x8 = (unsigned char*)(ws + 51511296);            //  2,097,152
    double* ri64 = (double*)(ws + 53608448);                        //    402,432
    unsigned long long* cpk = (unsigned long long*)(ws + 54010880); // 77,266,944
    unsigned char* cnt8 = (unsigned char*)(ws + 131277824);         //    804,864

    k_init <<<NTOK, 256, 0, stream>>>(x, x8);
    k_wnorm<<<OPAD, 256, 0, stream>>>(wgt, w8, ri64);
    k_gemm <<<NBLK, 256, 0, stream>>>(x8, w8, cpk, cnt8, out);
    k_sel  <<<NTOK, 256, 0, stream>>>(x, wgt, bias, cpk, cnt8, ri64, out);
}

// Round 17
// 553.381 us; speedup vs baseline: 1.4501x; 1.4501x over previous
//
#include <hip/hip_runtime.h>

#define NTOK 2048
#define DIM  1024          // K elements; == bytes for fp8
#define OUTD 50257
#define OPAD 50304         // 393*128
#define NCB  393           // column blocks (128 wide)
#define SEGC 12            // slots per (row, colblock) segment
#define TOPK 32
#define RCAP 256           // refine capacity (determinism: nref<=RCAP always)
#define NREF 80            // exact-refine depth (8.9 sigma rank margin vs fp8 coarse noise)
#define THRESH 0.08f
#define NBLK 6288          // gemm grid: 16 M-tiles(128) x 393 col-blocks

typedef float f32x4 __attribute__((ext_vector_type(4)));

// ---- f32 -> OCP e4m3fn, RNE, saturating (hand-rolled: no API risk) -------
__device__ __forceinline__ unsigned int f2e4m3(float f){
    unsigned int u = __float_as_uint(f);
    unsigned int sgn = (u >> 24) & 0x80u;
    int exp = (int)((u >> 23) & 0xFF);
    unsigned int man = u & 0x7FFFFF;
    int e = exp - 127;
    if (e >= 9) return sgn | 0x7E;                 // saturate to 448
    unsigned int full = 0x800000u | man;           // 24-bit significand
    int shift = (e >= -6) ? 20 : 20 + (-6 - e);    // subnormal extra shift
    if (shift >= 24) return sgn;                   // -> 0 (also f32 subnorm/0)
    unsigned int kept = full >> shift;
    unsigned int rem  = full & ((1u << shift) - 1);
    unsigned int half = 1u << (shift - 1);
    if (rem > half || (rem == half && (kept & 1))) kept++;
    if (e >= -6){
        unsigned int ee = (unsigned)(e + 7);
        if (kept >= 16){ kept >>= 1; ee++; }
        if (ee > 15 || (ee == 15 && (kept & 7) > 6)) return sgn | 0x7E;
        return sgn | (ee << 3) | (kept - 8);
    } else {
        if (kept >= 8) return sgn | 0x08;          // rounds up to min normal
        return sgn | kept;                         // subnormal
    }
}
__device__ __forceinline__ unsigned int pack4_e4m3(float a, float b, float c, float d){
    return f2e4m3(a) | (f2e4m3(b) << 8) | (f2e4m3(c) << 16) | (f2e4m3(d) << 24);
}

#define GLDS(gp, lp) __builtin_amdgcn_global_load_lds( \
    (__attribute__((address_space(1))) void*)(gp),     \
    (__attribute__((address_space(3))) void*)(lp), 16, 0, 0)

// ------- kernel 1: x-row L2-normalize, x8 = e4m3(32 * x_hat) --------------
extern "C" __global__ void k_init(const float* __restrict__ x,
                                  unsigned char* __restrict__ x8){
    __shared__ double ls[4];
    const int row = blockIdx.x, t = threadIdx.x;
    float4 v = ((const float4*)(x + (size_t)row * DIM))[t];
    double s = (double)v.x*v.x + (double)v.y*v.y
             + (double)v.z*v.z + (double)v.w*v.w;
    for (int d = 32; d >= 1; d >>= 1) s += __shfl_xor(s, d, 64);
    const int wv = t >> 6, ln = t & 63;
    if (ln == 0) ls[wv] = s;
    __syncthreads();
    double tot = ls[0] + ls[1] + ls[2] + ls[3];
    float sc = (float)(32.0 / fmax(sqrt(tot), 1e-12));
    ((unsigned int*)(x8 + (size_t)row * DIM))[t] =
        pack4_e4m3(v.x*sc, v.y*sc, v.z*sc, v.w*sc);
}

// ------- kernel 2: w8 = e4m3(32 * w_hat); ri64 = 1/max(||w||,eps) ---------
extern "C" __global__ void k_wnorm(const float* __restrict__ w,
                                   unsigned char* __restrict__ w8,
                                   double* __restrict__ ri64){
    __shared__ double ls[4];
    int r = blockIdx.x, t = threadIdx.x;
    if (r < OUTD){
        float4 v = ((const float4*)(w + (size_t)r * DIM))[t];
        double s = (double)v.x*v.x + (double)v.y*v.y
                 + (double)v.z*v.z + (double)v.w*v.w;
        for (int d = 32; d >= 1; d >>= 1) s += __shfl_xor(s, d, 64);
        int wv = t >> 6, ln = t & 63;
        if (ln == 0) ls[wv] = s;
        __syncthreads();
        double tot = ls[0] + ls[1] + ls[2] + ls[3];
        double ri = 1.0 / fmax(sqrt(tot), 1e-12);
        if (t == 0) ri64[r] = ri;
        float sc = (float)(32.0 * ri);
        ((unsigned int*)(w8 + (size_t)r * DIM))[t] =
            pack4_e4m3(v.x*sc, v.y*sc, v.z*sc, v.w*sc);
    } else { // pad rows: zero -> acc 0 -> filtered
        ((unsigned int*)(w8 + (size_t)r * DIM))[t] = 0u;
        if (t == 0) ri64[r] = 0.0;
    }
}

// ------ kernel 3: fp8 MFMA GEMM (4 waves 2x2, 64x64/wave, BK=32, dbuf) ----
// [R13 exact revert — 303us measured. MX 32x32x64 retired after two spill
//  failures (R10, R16: VGPR 256, +400MB scratch, occ 10%).]
// Out-zeroing AMORTIZED: 1 float4 store/thread/iter for 16 iters; those
// barriers use counted vmcnt(1) (GLDSs older than the store retire; store
// stays in flight across the barrier). Queue audit: each VBARZ leaves <=1
// outstanding; next barrier retires the previous prefetch before its
// buffer is read -> safe for wave-uniform store-skip blocks too.
// Epilogue: ATOMIC-FREE segmented candidate store (LDS counters only).
#define COMPUTE(b) do { \
  long af_[4], bv_[4]; \
  const char* Ab_ = As[b] + (lk>>1)*2048 + (lk&1)*8; \
  const char* Bb_ = Bs[b] + (lk>>1)*2048 + (lk&1)*8; \
  _Pragma("unroll") \
  for (int m_ = 0; m_ < 4; ++m_) \
    af_[m_] = *(const long*)(Ab_ + (wm*64 + m_*16 + lr)*16); \
  _Pragma("unroll") \
  for (int n_ = 0; n_ < 4; ++n_) \
    bv_[n_] = *(const long*)(Bb_ + (wn*64 + n_*16 + lr)*16); \
  __builtin_amdgcn_s_setprio(1); \
  _Pragma("unroll") \
  for (int m_ = 0; m_ < 4; ++m_) \
    _Pragma("unroll") \
    for (int n_ = 0; n_ < 4; ++n_) \
      acc[m_][n_] = __builtin_amdgcn_mfma_f32_16x16x32_fp8_fp8( \
                        af_[m_], bv_[n_], acc[m_][n_], 0, 0, 0); \
  __builtin_amdgcn_s_setprio(0); \
} while(0)

#define STAGE(b, K0) do { \
  GLDS(x8 + offA + (K0), As[b] + dstOff); \
  GLDS(w8 + offB + (K0), Bs[b] + dstOff); \
} while(0)

#define VBARZ() do { \
  asm volatile("s_waitcnt vmcnt(1)" ::: "memory"); \
  __builtin_amdgcn_s_barrier(); \
  asm volatile("" ::: "memory"); \
} while(0)

extern "C" __global__ __launch_bounds__(256)
void k_gemm(const unsigned char* __restrict__ x8,
            const unsigned char* __restrict__ w8,
            unsigned long long* __restrict__ cpk,
            unsigned char* __restrict__ cnt8,
            float* __restrict__ out){
    __shared__ __align__(16) char As[2][4096];
    __shared__ __align__(16) char Bs[2][4096];
    __shared__ int lcnt[128];
    const int tid = threadIdx.x;

    // bijective chunked XCD remap: 6288 = 8*786
    const int orig  = blockIdx.x;
    const int newid = (orig & 7) * 786 + (orig >> 3);
    const int bm    = (newid & 15) * 128;
    const int cb    = newid >> 4;               // column block 0..392
    const int bn    = cb * 128;

    const int wv = tid >> 6, lane = tid & 63;
    const int wm = wv >> 1,  wn = wv & 1;       // 2x2 waves, 64x64 each
    const int lr = lane & 15, lk = lane >> 4;

    if (tid < 128) lcnt[tid] = 0;

    f32x4 z = {0.f, 0.f, 0.f, 0.f};
    f32x4 acc[4][4];
    for (int m = 0; m < 4; ++m) for (int n = 0; n < 4; ++n) acc[m][n] = z;

    // staging: 256 segs of 16B per matrix per K-step; 1 each (A,B)/thread
    // (wave-contiguous: dst = wave base + lane*16 — m104-safe)
    const int srow   = tid & 127;
    const int sh     = tid >> 7;                // 16B-half within BK=32
    const int dstOff = sh*2048 + srow*16;       // pair-subtiled, wave-linear
    const size_t offA = (size_t)(bm + srow)*DIM + sh*16;
    const size_t offB = (size_t)(bn + srow)*DIM + sh*16;

    const size_t n4 = (size_t)NTOK * OUTD / 4;  // 25,731,584
    const float4 z4 = make_float4(0.f, 0.f, 0.f, 0.f);

    STAGE(0, 0);
    __syncthreads();                 // buf0 staged; lcnt init visible
    int buf = 0, it = 0;
    for (int k0 = 32; k0 < DIM; k0 += 32, ++it){
        STAGE(buf ^ 1, k0);          // prefetch next K-step
        if (it < 16){                // amortized zero slice (issued after STAGE)
            size_t zi = ((size_t)orig*16 + it)*256 + tid;
            if (zi < n4) ((float4*)out)[zi] = z4;
        }
        COMPUTE(buf);                // 8 ds_read_b64 + 16 MFMA
        if (it < 16) VBARZ();        // counted: store stays in flight
        else        __syncthreads();
        buf ^= 1;
    }
    COMPUTE(buf);

    // epilogue: cos = acc/1024; append to this block's (row, cb) segments
    const float inv = 1.0f / 1024.0f;
    #pragma unroll
    for (int n = 0; n < 4; ++n){
        int gcol = bn + wn*64 + n*16 + lr;
        bool ok = gcol < OUTD;
        #pragma unroll
        for (int m = 0; m < 4; ++m){
            int lr0 = wm*64 + m*16 + lk*4;        // local row (C/D layout)
            #pragma unroll
            for (int r = 0; r < 4; ++r){
                float sc = acc[m][n][r] * inv;
                if (ok && sc > THRESH){
                    int lrow = lr0 + r;
                    int pos = atomicAdd(&lcnt[lrow], 1);   // LDS atomic only
                    if (pos < SEGC)
                        cpk[((size_t)(bm + lrow)*NCB + cb)*SEGC + pos] =
                            ((unsigned long long)(unsigned)gcol << 32) |
                            (unsigned long long)__float_as_uint(sc);
                }
            }
        }
    }
    __syncthreads();                 // drains cpk stores (few/thread) only
    if (tid < 128)
        cnt8[(size_t)(bm + tid)*NCB + cb] =
            (unsigned char)min(lcnt[tid], SEGC);
}

// -------- kernel 4: select + f64 refine + scatter (zeroing in gemm) -------
// Determinism: refine SET = {candidates in bins >= bstar} is order-invariant;
// segment contents are set-complete (cap-12 overflow prob ~3e-7/run);
// f64 scores + (score desc, idx asc) sort -> arrival-order independent.
// R17: refine processes 2 candidates per wave concurrently (2 independent
// gather streams + 2 f64 chains; per-candidate summation order unchanged
// -> bitwise-identical results) to double memory-level parallelism.
extern "C" __global__ __launch_bounds__(256)
void k_sel(const float* __restrict__ x, const float* __restrict__ w,
           const float* __restrict__ bias,
           const unsigned long long* __restrict__ cpk,
           const unsigned char* __restrict__ cnt8,
           const double* __restrict__ ri64,
           float* __restrict__ out){
    const int row = blockIdx.x, tid = threadIdx.x;
    __shared__ float  xl[DIM];
    __shared__ int    hist[256];
    __shared__ int    bstar, nref;
    __shared__ int    ridx[RCAP];
    __shared__ double rsc[RCAP];
    __shared__ double rdv[RCAP];

    ((float4*)xl)[tid] = ((const float4*)(x + (size_t)row*DIM))[tid];
    hist[tid] = 0;
    if (tid == 0) nref = 0;
    __syncthreads();

    const unsigned char* rc8 = cnt8 + (size_t)row*NCB;
    const unsigned long long* rseg = cpk + (size_t)row*NCB*SEGC;

    // histogram of coarse scores (bins of 7.8e-4 over [0.08, 0.28])
    for (int cb = tid; cb < NCB; cb += 256){
        int c = rc8[cb];
        for (int j = 0; j < c; ++j){
            float s = __uint_as_float((unsigned)(rseg[cb*SEGC + j] & 0xFFFFFFFFu));
            int b = (int)((s - THRESH) * 1280.f);
            b = max(0, min(255, b));
            atomicAdd(&hist[b], 1);
        }
    }
    __syncthreads();
    if (tid == 0){  // smallest bin whose top-cumulative >= NREF
        int cum = 0, b = 255;
        for (; b >= 0; --b){ cum += hist[b]; if (cum >= NREF) break; }
        bstar = b < 0 ? 0 : b;
    }
    __syncthreads();
    const int bs_ = bstar;
    for (int cb = tid; cb < NCB; cb += 256){
        int c = rc8[cb];
        for (int j = 0; j < c; ++j){
            unsigned long long pk = rseg[cb*SEGC + j];
            float s = __uint_as_float((unsigned)(pk & 0xFFFFFFFFu));
            int b = (int)((s - THRESH) * 1280.f);
            b = max(0, min(255, b));
            if (b >= bs_){
                int p = atomicAdd(&nref, 1);
                if (p < RCAP) ridx[p] = (int)(pk >> 32);
            }
        }
    }
    __syncthreads();
    const int nr = min(nref, RCAP);

    // f64 refine: TWO candidates per wave concurrently (ILP), float4 loads
    const int wv = tid >> 6, lane = tid & 63;
    const float4* xl4 = (const float4*)xl;
    for (int q0 = 2*wv; q0 < nr; q0 += 8){
        const int q1 = q0 + 1;
        const bool has1 = q1 < nr;
        int col0 = ridx[q0];
        int col1 = has1 ? ridx[q1] : col0;
        const float4* w0 = (const float4*)(w + (size_t)col0*DIM);
        const float4* w1 = (const float4*)(w + (size_t)col1*DIM);
        double s0 = 0.0, s1 = 0.0;
        #pragma unroll
        for (int u = 0; u < 4; ++u){
            float4 a  = xl4[lane + 64*u];
            float4 b0 = w0[lane + 64*u];
            float4 b1 = w1[lane + 64*u];
            s0 = fma((double)a.x, (double)b0.x, s0);
            s0 = fma((double)a.y, (double)b0.y, s0);
            s0 = fma((double)a.z, (double)b0.z, s0);
            s0 = fma((double)a.w, (double)b0.w, s0);
            s1 = fma((double)a.x, (double)b1.x, s1);
            s1 = fma((double)a.y, (double)b1.y, s1);
            s1 = fma((double)a.z, (double)b1.z, s1);
            s1 = fma((double)a.w, (double)b1.w, s1);
        }
        for (int d = 32; d >= 1; d >>= 1){
            s0 += __shfl_xor(s0, d, 64);
            s1 += __shfl_xor(s1, d, 64);
        }
        if (lane == 0){
            rdv[q0] = s0; rsc[q0] = s0 * ri64[col0];
            if (has1){ rdv[q1] = s1; rsc[q1] = s1 * ri64[col1]; }
        }
    }
    __syncthreads();
    if (tid >= nr){ rsc[tid] = -1.0e300; ridx[tid] = 0x7FFFFFFF; rdv[tid] = 0.0; }
    __syncthreads();

    // bitonic sort 256: descending score, ties -> smaller index
    for (int k = 2; k <= RCAP; k <<= 1){
        for (int j = k >> 1; j > 0; j >>= 1){
            int i = tid, ixj = i ^ j;
            if (ixj > i){
                double sa = rsc[i], sb = rsc[ixj];
                int ia = ridx[i], ib = ridx[ixj];
                bool dir = ((i & k) == 0);
                bool pb = (sb > sa) || (sb == sa && ib < ia);
                if (pb == dir){
                    rsc[i] = sb; rsc[ixj] = sa;
                    ridx[i] = ib; ridx[ixj] = ia;
                    double t = rdv[i]; rdv[i] = rdv[ixj]; rdv[ixj] = t;
                }
            }
            __syncthreads();
        }
    }
    if (tid < TOPK && tid < nr){
        int col = ridx[tid];
        out[(size_t)row*OUTD + col] = (float)rdv[tid] + bias[col];
    }
}

// ---------------- launch --------------------------------------------------
extern "C" void kernel_launch(void* const* d_in, const int* in_sizes, int n_in,
                              void* d_out, int out_size, void* d_ws, size_t ws_size,
                              hipStream_t stream){
    const float* x    = (const float*)d_in[0];
    const float* wgt  = (const float*)d_in[1];
    const float* bias = (const float*)d_in[2];
    float* out = (float*)d_out;
    char* ws = (char*)d_ws;

    // workspace carve (~132 MB)
    unsigned char* w8 = (unsigned char*)ws;                         // 51,511,296
    unsigned char* x8 = (unsigned char*)(ws + 51511296);            //  2,097,152
    double* ri64 = (double*)(ws + 53608448);                        //    402,432
    unsigned long long* cpk = (unsigned long long*)(ws + 54010880); // 77,266,944
    unsigned char* cnt8 = (unsigned char*)(ws + 131277824);         //    804,864

    k_init <<<NTOK, 256, 0, stream>>>(x, x8);
    k_wnorm<<<OPAD, 256, 0, stream>>>(wgt, w8, ri64);
    k_gemm <<<NBLK, 256, 0, stream>>>(x8, w8, cpk, cnt8, out);
    k_sel  <<<NTOK, 256, 0, stream>>>(x, wgt, bias, cpk, cnt8, ri64, out);
}

// Round 18
// 526.432 us; speedup vs baseline: 1.5243x; 1.0512x over previous
//
#include <hip/hip_runtime.h>

#define NTOK 2048
#define DIM  1024          // K elements; == bytes for fp8
#define OUTD 50257
#define OPAD 50304         // 393*128
#define NCB  393           // column blocks (128 wide)
#define SEGC 12            // slots per (row, colblock) segment
#define TOPK 32
#define RCAP 256           // refine capacity (determinism: nref<=RCAP always)
#define NREF 80            // exact-refine depth (8.9 sigma rank margin vs fp8 coarse noise)
#define THRESH 0.08f
#define NBLK 6288          // gemm grid: 16 M-tiles(128) x 393 col-blocks

typedef float f32x4 __attribute__((ext_vector_type(4)));

// ---- f32 -> OCP e4m3fn, RNE, saturating (hand-rolled: no API risk) -------
__device__ __forceinline__ unsigned int f2e4m3(float f){
    unsigned int u = __float_as_uint(f);
    unsigned int sgn = (u >> 24) & 0x80u;
    int exp = (int)((u >> 23) & 0xFF);
    unsigned int man = u & 0x7FFFFF;
    int e = exp - 127;
    if (e >= 9) return sgn | 0x7E;                 // saturate to 448
    unsigned int full = 0x800000u | man;           // 24-bit significand
    int shift = (e >= -6) ? 20 : 20 + (-6 - e);    // subnormal extra shift
    if (shift >= 24) return sgn;                   // -> 0 (also f32 subnorm/0)
    unsigned int kept = full >> shift;
    unsigned int rem  = full & ((1u << shift) - 1);
    unsigned int half = 1u << (shift - 1);
    if (rem > half || (rem == half && (kept & 1))) kept++;
    if (e >= -6){
        unsigned int ee = (unsigned)(e + 7);
        if (kept >= 16){ kept >>= 1; ee++; }
        if (ee > 15 || (ee == 15 && (kept & 7) > 6)) return sgn | 0x7E;
        return sgn | (ee << 3) | (kept - 8);
    } else {
        if (kept >= 8) return sgn | 0x08;          // rounds up to min normal
        return sgn | kept;                         // subnormal
    }
}
__device__ __forceinline__ unsigned int pack4_e4m3(float a, float b, float c, float d){
    return f2e4m3(a) | (f2e4m3(b) << 8) | (f2e4m3(c) << 16) | (f2e4m3(d) << 24);
}

#define GLDS(gp, lp) __builtin_amdgcn_global_load_lds( \
    (__attribute__((address_space(1))) void*)(gp),     \
    (__attribute__((address_space(3))) void*)(lp), 16, 0, 0)

// ------- kernel 1: x-row L2-normalize, x8 = e4m3(32 * x_hat) --------------
extern "C" __global__ void k_init(const float* __restrict__ x,
                                  unsigned char* __restrict__ x8){
    __shared__ double ls[4];
    const int row = blockIdx.x, t = threadIdx.x;
    float4 v = ((const float4*)(x + (size_t)row * DIM))[t];
    double s = (double)v.x*v.x + (double)v.y*v.y
             + (double)v.z*v.z + (double)v.w*v.w;
    for (int d = 32; d >= 1; d >>= 1) s += __shfl_xor(s, d, 64);
    const int wv = t >> 6, ln = t & 63;
    if (ln == 0) ls[wv] = s;
    __syncthreads();
    double tot = ls[0] + ls[1] + ls[2] + ls[3];
    float sc = (float)(32.0 / fmax(sqrt(tot), 1e-12));
    ((unsigned int*)(x8 + (size_t)row * DIM))[t] =
        pack4_e4m3(v.x*sc, v.y*sc, v.z*sc, v.w*sc);
}

// ------- kernel 2: w8 = e4m3(32 * w_hat); ri64 = 1/max(||w||,eps) ---------
extern "C" __global__ void k_wnorm(const float* __restrict__ w,
                                   unsigned char* __restrict__ w8,
                                   double* __restrict__ ri64){
    __shared__ double ls[4];
    int r = blockIdx.x, t = threadIdx.x;
    if (r < OUTD){
        float4 v = ((const float4*)(w + (size_t)r * DIM))[t];
        double s = (double)v.x*v.x + (double)v.y*v.y
                 + (double)v.z*v.z + (double)v.w*v.w;
        for (int d = 32; d >= 1; d >>= 1) s += __shfl_xor(s, d, 64);
        int wv = t >> 6, ln = t & 63;
        if (ln == 0) ls[wv] = s;
        __syncthreads();
        double tot = ls[0] + ls[1] + ls[2] + ls[3];
        double ri = 1.0 / fmax(sqrt(tot), 1e-12);
        if (t == 0) ri64[r] = ri;
        float sc = (float)(32.0 * ri);
        ((unsigned int*)(w8 + (size_t)r * DIM))[t] =
            pack4_e4m3(v.x*sc, v.y*sc, v.z*sc, v.w*sc);
    } else { // pad rows: zero -> acc 0 -> filtered
        ((unsigned int*)(w8 + (size_t)r * DIM))[t] = 0u;
        if (t == 0) ri64[r] = 0.0;
    }
}

// ------ kernel 3: fp8 MFMA GEMM, BK=64, RING-3 LDS, depth-2 prefetch ------
// 128x128 tile, 4 waves 2x2 (64x64/wave, proven R9 fragment math), 16 K-tiles.
// LDS per buffer: [4 kchunks][128 rows][16B] = 8KB each for A,B; 3 buffers.
// At iter-t wait, tile-t's loads are ~2 iterations old -> near-zero stall.
// Per-iter queue is UNIFORM {4 GLDS, 1 store} (zero-store clamped so every
// wave always issues it — fixes R13's latent boundary-wave miscount).
// Counted waits (in-order vmcnt retirement, m135): ops newer than tile-t's
// 4 loads = 9 (t=0), 10 (t=1), 11 (t=2..13), 7 (t=14), 3 (t=15).
// Barriers also drain lgkmcnt(0) (LDS visibility for lcnt / ds_reads).
#define COMPUTE(b) do { \
  _Pragma("unroll") \
  for (int ks_ = 0; ks_ < 2; ++ks_){ \
    long af_[4], bv_[4]; \
    const char* Ab_ = As[b] + (ks_*2 + (lk>>1))*2048 + (lk&1)*8; \
    const char* Bb_ = Bs[b] + (ks_*2 + (lk>>1))*2048 + (lk&1)*8; \
    _Pragma("unroll") \
    for (int m_ = 0; m_ < 4; ++m_) \
      af_[m_] = *(const long*)(Ab_ + (wm*64 + m_*16 + lr)*16); \
    _Pragma("unroll") \
    for (int n_ = 0; n_ < 4; ++n_) \
      bv_[n_] = *(const long*)(Bb_ + (wn*64 + n_*16 + lr)*16); \
    __builtin_amdgcn_s_setprio(1); \
    _Pragma("unroll") \
    for (int m_ = 0; m_ < 4; ++m_) \
      _Pragma("unroll") \
      for (int n_ = 0; n_ < 4; ++n_) \
        acc[m_][n_] = __builtin_amdgcn_mfma_f32_16x16x32_fp8_fp8( \
                          af_[m_], bv_[n_], acc[m_][n_], 0, 0, 0); \
    __builtin_amdgcn_s_setprio(0); \
  } \
} while(0)

#define STAGE(b, K0) do { \
  GLDS(x8 + offA0 + (K0), As[b] + tid*16); \
  GLDS(x8 + offA0 + 32 + (K0), As[b] + (tid+256)*16); \
  GLDS(w8 + offB0 + (K0), Bs[b] + tid*16); \
  GLDS(w8 + offB0 + 32 + (K0), Bs[b] + (tid+256)*16); \
} while(0)

#define ZSTORE(IT) do { \
  size_t zi_ = ((size_t)orig*16 + (IT))*256 + tid; \
  if (zi_ >= n4) zi_ = n4 - 1;     /* idempotent; keeps queue uniform */ \
  ((float4*)out)[zi_] = z4; \
} while(0)

#define VBL(N) do { \
  asm volatile("s_waitcnt vmcnt(" #N ") lgkmcnt(0)" ::: "memory"); \
  __builtin_amdgcn_s_barrier(); \
  asm volatile("" ::: "memory"); \
} while(0)

#define EBAR() do { \
  __builtin_amdgcn_s_barrier(); \
  asm volatile("" ::: "memory"); \
} while(0)

extern "C" __global__ __launch_bounds__(256)
void k_gemm(const unsigned char* __restrict__ x8,
            const unsigned char* __restrict__ w8,
            unsigned long long* __restrict__ cpk,
            unsigned char* __restrict__ cnt8,
            float* __restrict__ out){
    __shared__ __align__(16) char As[3][8192];
    __shared__ __align__(16) char Bs[3][8192];
    __shared__ int lcnt[128];
    const int tid = threadIdx.x;

    // bijective chunked XCD remap: 6288 = 8*786
    const int orig  = blockIdx.x;
    const int newid = (orig & 7) * 786 + (orig >> 3);
    const int bm    = (newid & 15) * 128;
    const int cb    = newid >> 4;               // column block 0..392
    const int bn    = cb * 128;

    const int wv = tid >> 6, lane = tid & 63;
    const int wm = wv >> 1,  wn = wv & 1;       // 2x2 waves, 64x64 each
    const int lr = lane & 15, lk = lane >> 4;

    if (tid < 128) lcnt[tid] = 0;

    f32x4 z = {0.f, 0.f, 0.f, 0.f};
    f32x4 acc[4][4];
    for (int m = 0; m < 4; ++m) for (int n = 0; n < 4; ++n) acc[m][n] = z;

    // staging map: 512 16B segs per matrix per K-tile; 2 each (A,B)/thread.
    // seg = tid (kchunks 0-1) and tid+256 (kchunks 2-3); row = tid&127.
    // dst = seg*16: wave-contiguous (m104-safe).
    const size_t offA0 = (size_t)(bm + (tid & 127))*DIM + (tid >> 7)*16;
    const size_t offB0 = (size_t)(bn + (tid & 127))*DIM + (tid >> 7)*16;

    const size_t n4 = (size_t)NTOK * OUTD / 4;  // 25,731,584
    const float4 z4 = make_float4(0.f, 0.f, 0.f, 0.f);

    // ---- ring-3 pipeline over 16 K-tiles (BK=64) ----
    STAGE(0, 0);
    STAGE(1, 64);
    // t=0
    STAGE(2, 128); ZSTORE(0);  VBL(9);  COMPUTE(0); EBAR();
    // t=1
    STAGE(0, 192); ZSTORE(1);  VBL(10); COMPUTE(1); EBAR();
    // t=2..13
    {
        int bufS = 1, bufC = 2;
        for (int t = 2; t <= 13; ++t){
            STAGE(bufS, (t+2)*64);
            ZSTORE(t);
            VBL(11);
            COMPUTE(bufC);
            EBAR();
            bufS = (bufS == 2) ? 0 : bufS + 1;
            bufC = (bufC == 2) ? 0 : bufC + 1;
        }
    }
    // t=14 (no stage)
    ZSTORE(14); VBL(7); COMPUTE(2); EBAR();
    // t=15 (no stage)
    ZSTORE(15); VBL(3); COMPUTE(0);

    // epilogue: cos = acc/1024; append to this block's (row, cb) segments
    const float inv = 1.0f / 1024.0f;
    #pragma unroll
    for (int n = 0; n < 4; ++n){
        int gcol = bn + wn*64 + n*16 + lr;
        bool ok = gcol < OUTD;
        #pragma unroll
        for (int m = 0; m < 4; ++m){
            int lr0 = wm*64 + m*16 + lk*4;        // local row (C/D layout)
            #pragma unroll
            for (int r = 0; r < 4; ++r){
                float sc = acc[m][n][r] * inv;
                if (ok && sc > THRESH){
                    int lrow = lr0 + r;
                    int pos = atomicAdd(&lcnt[lrow], 1);   // LDS atomic only
                    if (pos < SEGC)
                        cpk[((size_t)(bm + lrow)*NCB + cb)*SEGC + pos] =
                            ((unsigned long long)(unsigned)gcol << 32) |
                            (unsigned long long)__float_as_uint(sc);
                }
            }
        }
    }
    __syncthreads();                 // drains cpk + trailing zero stores
    if (tid < 128)
        cnt8[(size_t)(bm + tid)*NCB + cb] =
            (unsigned char)min(lcnt[tid], SEGC);
}

// -------- kernel 4: select + f64 refine + scatter (zeroing in gemm) -------
// Determinism: refine SET = {candidates in bins >= bstar} is order-invariant;
// segment contents are set-complete (cap-12 overflow prob ~3e-7/run);
// f64 scores + (score desc, idx asc) sort -> arrival-order independent.
extern "C" __global__ __launch_bounds__(256)
void k_sel(const float* __restrict__ x, const float* __restrict__ w,
           const float* __restrict__ bias,
           const unsigned long long* __restrict__ cpk,
           const unsigned char* __restrict__ cnt8,
           const double* __restrict__ ri64,
           float* __restrict__ out){
    const int row = blockIdx.x, tid = threadIdx.x;
    __shared__ float  xl[DIM];
    __shared__ int    hist[256];
    __shared__ int    bstar, nref;
    __shared__ int    ridx[RCAP];
    __shared__ double rsc[RCAP];
    __shared__ double rdv[RCAP];

    ((float4*)xl)[tid] = ((const float4*)(x + (size_t)row*DIM))[tid];
    hist[tid] = 0;
    if (tid == 0) nref = 0;
    __syncthreads();

    const unsigned char* rc8 = cnt8 + (size_t)row*NCB;
    const unsigned long long* rseg = cpk + (size_t)row*NCB*SEGC;

    // histogram of coarse scores (bins of 7.8e-4 over [0.08, 0.28])
    for (int cb = tid; cb < NCB; cb += 256){
        int c = rc8[cb];
        for (int j = 0; j < c; ++j){
            float s = __uint_as_float((unsigned)(rseg[cb*SEGC + j] & 0xFFFFFFFFu));
            int b = (int)((s - THRESH) * 1280.f);
            b = max(0, min(255, b));
            atomicAdd(&hist[b], 1);
        }
    }
    __syncthreads();
    if (tid == 0){  // smallest bin whose top-cumulative >= NREF
        int cum = 0, b = 255;
        for (; b >= 0; --b){ cum += hist[b]; if (cum >= NREF) break; }
        bstar = b < 0 ? 0 : b;
    }
    __syncthreads();
    const int bs_ = bstar;
    for (int cb = tid; cb < NCB; cb += 256){
        int c = rc8[cb];
        for (int j = 0; j < c; ++j){
            unsigned long long pk = rseg[cb*SEGC + j];
            float s = __uint_as_float((unsigned)(pk & 0xFFFFFFFFu));
            int b = (int)((s - THRESH) * 1280.f);
            b = max(0, min(255, b));
            if (b >= bs_){
                int p = atomicAdd(&nref, 1);
                if (p < RCAP) ridx[p] = (int)(pk >> 32);
            }
        }
    }
    __syncthreads();
    const int nr = min(nref, RCAP);

    // f64 refine: one wave per candidate, float4-vectorized loads
    const int wv = tid >> 6, lane = tid & 63;
    const float4* xl4 = (const float4*)xl;
    for (int q = wv; q < nr; q += 4){
        int col = ridx[q];
        const float4* wr4 = (const float4*)(w + (size_t)col*DIM);
        double s = 0.0;
        #pragma unroll
        for (int u = 0; u < 4; ++u){
            float4 a = xl4[lane + 64*u];
            float4 b = wr4[lane + 64*u];
            s = fma((double)a.x, (double)b.x, s);
            s = fma((double)a.y, (double)b.y, s);
            s = fma((double)a.z, (double)b.z, s);
            s = fma((double)a.w, (double)b.w, s);
        }
        for (int d = 32; d >= 1; d >>= 1) s += __shfl_xor(s, d, 64);
        if (lane == 0){ rdv[q] = s; rsc[q] = s * ri64[col]; }
    }
    __syncthreads();
    if (tid >= nr){ rsc[tid] = -1.0e300; ridx[tid] = 0x7FFFFFFF; rdv[tid] = 0.0; }
    __syncthreads();

    // bitonic sort 256: descending score, ties -> smaller index
    for (int k = 2; k <= RCAP; k <<= 1){
        for (int j = k >> 1; j > 0; j >>= 1){
            int i = tid, ixj = i ^ j;
            if (ixj > i){
                double sa = rsc[i], sb = rsc[ixj];
                int ia = ridx[i], ib = ridx[ixj];
                bool dir = ((i & k) == 0);
                bool pb = (sb > sa) || (sb == sa && ib < ia);
                if (pb == dir){
                    rsc[i] = sb; rsc[ixj] = sa;
                    ridx[i] = ib; ridx[ixj] = ia;
                    double t = rdv[i]; rdv[i] = rdv[ixj]; rdv[ixj] = t;
                }
            }
            __syncthreads();
        }
    }
    if (tid < TOPK && tid < nr){
        int col = ridx[tid];
        out[(size_t)row*OUTD + col] = (float)rdv[tid] + bias[col];
    }
}

// ---------------- launch --------------------------------------------------
extern "C" void kernel_launch(void* const* d_in, const int* in_sizes, int n_in,
                              void* d_out, int out_size, void* d_ws, size_t ws_size,
                              hipStream_t stream){
    const float* x    = (const float*)d_in[0];
    const float* wgt  = (const float*)d_in[1];
    const float* bias = (const float*)d_in[2];
    float* out = (float*)d_out;
    char* ws = (char*)d_ws;

    // workspace carve (~132 MB)
    unsigned char* w8 = (unsigned char*)ws;                         // 51,511,296
    unsigned char* x8 = (unsigned char*)(ws + 51511296);            //  2,097,152
    double* ri64 = (double*)(ws + 53608448);                        //    402,432
    unsigned long long* cpk = (unsigned long long*)(ws + 54010880); // 77,266,944
    unsigned char* cnt8 = (unsigned char*)(ws + 131277824);         //    804,864

    k_init <<<NTOK, 256, 0, stream>>>(x, x8);
    k_wnorm<<<OPAD, 256, 0, stream>>>(wgt, w8, ri64);
    k_gemm <<<NBLK, 256, 0, stream>>>(x8, w8, cpk, cnt8, out);
    k_sel  <<<NTOK, 256, 0, stream>>>(x, wgt, bias, cpk, cnt8, ri64, out);
}

// Round 19
// 523.077 us; speedup vs baseline: 1.5341x; 1.0064x over previous
//
#include <hip/hip_runtime.h>

#define NTOK 2048
#define DIM  1024          // K elements; == bytes for fp8
#define OUTD 50257
#define OPAD 50304         // 393*128
#define NCB  393           // column blocks (128 wide)
#define SEGC 12            // slots per (row, colblock) segment
#define TOPK 32
#define RCAP 256           // refine capacity (determinism: nref<=RCAP always)
#define NREF 80            // exact-refine depth (vs fp8 coarse noise)
#define THRESH 0.08f
#define NBLK 6288          // gemm grid: 16 M-tiles(128) x 393 col-blocks

typedef float f32x4 __attribute__((ext_vector_type(4)));

// ---- f32 -> OCP e4m3fn, RNE, saturating (hand-rolled: no API risk) -------
__device__ __forceinline__ unsigned int f2e4m3(float f){
    unsigned int u = __float_as_uint(f);
    unsigned int sgn = (u >> 24) & 0x80u;
    int exp = (int)((u >> 23) & 0xFF);
    unsigned int man = u & 0x7FFFFF;
    int e = exp - 127;
    if (e >= 9) return sgn | 0x7E;                 // saturate to 448
    unsigned int full = 0x800000u | man;           // 24-bit significand
    int shift = (e >= -6) ? 20 : 20 + (-6 - e);    // subnormal extra shift
    if (shift >= 24) return sgn;                   // -> 0 (also f32 subnorm/0)
    unsigned int kept = full >> shift;
    unsigned int rem  = full & ((1u << shift) - 1);
    unsigned int half = 1u << (shift - 1);
    if (rem > half || (rem == half && (kept & 1))) kept++;
    if (e >= -6){
        unsigned int ee = (unsigned)(e + 7);
        if (kept >= 16){ kept >>= 1; ee++; }
        if (ee > 15 || (ee == 15 && (kept & 7) > 6)) return sgn | 0x7E;
        return sgn | (ee << 3) | (kept - 8);
    } else {
        if (kept >= 8) return sgn | 0x08;          // rounds up to min normal
        return sgn | kept;                         // subnormal
    }
}
__device__ __forceinline__ unsigned int pack4_e4m3(float a, float b, float c, float d){
    return f2e4m3(a) | (f2e4m3(b) << 8) | (f2e4m3(c) << 16) | (f2e4m3(d) << 24);
}

#define GLDS(gp, lp) __builtin_amdgcn_global_load_lds( \
    (__attribute__((address_space(1))) void*)(gp),     \
    (__attribute__((address_space(3))) void*)(lp), 16, 0, 0)

// ---- T2 half-swap swizzle (bank-conflict fix, rule #21 both-sides) -------
// Producer: for rows with s(row)=(row>>3)&1==1, the two 8B k-halves within
// every 16B granule are stored SWAPPED (dword index t ^ (s<<1)).
// Reader (k_gemm frag read): position hpos = (lk ^ (lr>>3)) & 1 — fetches
// the correct global k-half AND spreads each 16-lane phase across all 32
// banks (lr 0-7 -> banks {4lr,4lr+1}, lr 8-15 -> {4lr+2,4lr+3} mod 32).

// ------- kernel 1: x-row L2-normalize, x8 = e4m3(32 * x_hat) --------------
extern "C" __global__ void k_init(const float* __restrict__ x,
                                  unsigned char* __restrict__ x8){
    __shared__ double ls[4];
    const int row = blockIdx.x, t = threadIdx.x;
    float4 v = ((const float4*)(x + (size_t)row * DIM))[t];
    double s = (double)v.x*v.x + (double)v.y*v.y
             + (double)v.z*v.z + (double)v.w*v.w;
    for (int d = 32; d >= 1; d >>= 1) s += __shfl_xor(s, d, 64);
    const int wv = t >> 6, ln = t & 63;
    if (ln == 0) ls[wv] = s;
    __syncthreads();
    double tot = ls[0] + ls[1] + ls[2] + ls[3];
    float sc = (float)(32.0 / fmax(sqrt(tot), 1e-12));
    const int sw = ((row >> 3) & 1) << 1;        // T2 half-swap
    ((unsigned int*)(x8 + (size_t)row * DIM))[t ^ sw] =
        pack4_e4m3(v.x*sc, v.y*sc, v.z*sc, v.w*sc);
}

// ------- kernel 2: w8 = e4m3(32 * w_hat); ri64 = 1/max(||w||,eps) ---------
extern "C" __global__ void k_wnorm(const float* __restrict__ w,
                                   unsigned char* __restrict__ w8,
                                   double* __restrict__ ri64){
    __shared__ double ls[4];
    int r = blockIdx.x, t = threadIdx.x;
    const int sw = ((r >> 3) & 1) << 1;          // T2 half-swap
    if (r < OUTD){
        float4 v = ((const float4*)(w + (size_t)r * DIM))[t];
        double s = (double)v.x*v.x + (double)v.y*v.y
                 + (double)v.z*v.z + (double)v.w*v.w;
        for (int d = 32; d >= 1; d >>= 1) s += __shfl_xor(s, d, 64);
        int wv = t >> 6, ln = t & 63;
        if (ln == 0) ls[wv] = s;
        __syncthreads();
        double tot = ls[0] + ls[1] + ls[2] + ls[3];
        double ri = 1.0 / fmax(sqrt(tot), 1e-12);
        if (t == 0) ri64[r] = ri;
        float sc = (float)(32.0 * ri);
        ((unsigned int*)(w8 + (size_t)r * DIM))[t ^ sw] =
            pack4_e4m3(v.x*sc, v.y*sc, v.z*sc, v.w*sc);
    } else { // pad rows: zero -> acc 0 -> filtered
        ((unsigned int*)(w8 + (size_t)r * DIM))[t ^ sw] = 0u;
        if (t == 0) ri64[r] = 0.0;
    }
}

// ------ kernel 3: fp8 MFMA GEMM, BK=64, RING-3 LDS, depth-2 prefetch ------
// [R18 structure verbatim; only the frag-read half-position changed to the
//  T2 swizzle. Fragment k-assignment preserved: A-row = m*16+lr, B-row =
//  n*16+lr, both s = (lr>>3)&1, producer-swapped identically.]
#define COMPUTE(b) do { \
  const int hp_ = ((lk ^ (lr >> 3)) & 1) * 8;   /* T2 read position */ \
  _Pragma("unroll") \
  for (int ks_ = 0; ks_ < 2; ++ks_){ \
    long af_[4], bv_[4]; \
    const char* Ab_ = As[b] + (ks_*2 + (lk>>1))*2048 + hp_; \
    const char* Bb_ = Bs[b] + (ks_*2 + (lk>>1))*2048 + hp_; \
    _Pragma("unroll") \
    for (int m_ = 0; m_ < 4; ++m_) \
      af_[m_] = *(const long*)(Ab_ + (wm*64 + m_*16 + lr)*16); \
    _Pragma("unroll") \
    for (int n_ = 0; n_ < 4; ++n_) \
      bv_[n_] = *(const long*)(Bb_ + (wn*64 + n_*16 + lr)*16); \
    __builtin_amdgcn_s_setprio(1); \
    _Pragma("unroll") \
    for (int m_ = 0; m_ < 4; ++m_) \
      _Pragma("unroll") \
      for (int n_ = 0; n_ < 4; ++n_) \
        acc[m_][n_] = __builtin_amdgcn_mfma_f32_16x16x32_fp8_fp8( \
                          af_[m_], bv_[n_], acc[m_][n_], 0, 0, 0); \
    __builtin_amdgcn_s_setprio(0); \
  } \
} while(0)

#define STAGE(b, K0) do { \
  GLDS(x8 + offA0 + (K0), As[b] + tid*16); \
  GLDS(x8 + offA0 + 32 + (K0), As[b] + (tid+256)*16); \
  GLDS(w8 + offB0 + (K0), Bs[b] + tid*16); \
  GLDS(w8 + offB0 + 32 + (K0), Bs[b] + (tid+256)*16); \
} while(0)

#define ZSTORE(IT) do { \
  size_t zi_ = ((size_t)orig*16 + (IT))*256 + tid; \
  if (zi_ >= n4) zi_ = n4 - 1;     /* idempotent; keeps queue uniform */ \
  ((float4*)out)[zi_] = z4; \
} while(0)

#define VBL(N) do { \
  asm volatile("s_waitcnt vmcnt(" #N ") lgkmcnt(0)" ::: "memory"); \
  __builtin_amdgcn_s_barrier(); \
  asm volatile("" ::: "memory"); \
} while(0)

#define EBAR() do { \
  __builtin_amdgcn_s_barrier(); \
  asm volatile("" ::: "memory"); \
} while(0)

extern "C" __global__ __launch_bounds__(256)
void k_gemm(const unsigned char* __restrict__ x8,
            const unsigned char* __restrict__ w8,
            unsigned long long* __restrict__ cpk,
            unsigned char* __restrict__ cnt8,
            float* __restrict__ out){
    __shared__ __align__(16) char As[3][8192];
    __shared__ __align__(16) char Bs[3][8192];
    __shared__ int lcnt[128];
    const int tid = threadIdx.x;

    // bijective chunked XCD remap: 6288 = 8*786
    const int orig  = blockIdx.x;
    const int newid = (orig & 7) * 786 + (orig >> 3);
    const int bm    = (newid & 15) * 128;
    const int cb    = newid >> 4;               // column block 0..392
    const int bn    = cb * 128;

    const int wv = tid >> 6, lane = tid & 63;
    const int wm = wv >> 1,  wn = wv & 1;       // 2x2 waves, 64x64 each
    const int lr = lane & 15, lk = lane >> 4;

    if (tid < 128) lcnt[tid] = 0;

    f32x4 z = {0.f, 0.f, 0.f, 0.f};
    f32x4 acc[4][4];
    for (int m = 0; m < 4; ++m) for (int n = 0; n < 4; ++n) acc[m][n] = z;

    // staging map: 512 16B segs per matrix per K-tile; 2 each (A,B)/thread.
    // dst = seg*16: wave-contiguous (m104-safe).
    const size_t offA0 = (size_t)(bm + (tid & 127))*DIM + (tid >> 7)*16;
    const size_t offB0 = (size_t)(bn + (tid & 127))*DIM + (tid >> 7)*16;

    const size_t n4 = (size_t)NTOK * OUTD / 4;  // 25,731,584
    const float4 z4 = make_float4(0.f, 0.f, 0.f, 0.f);

    // ---- ring-3 pipeline over 16 K-tiles (BK=64) ----
    STAGE(0, 0);
    STAGE(1, 64);
    // t=0
    STAGE(2, 128); ZSTORE(0);  VBL(9);  COMPUTE(0); EBAR();
    // t=1
    STAGE(0, 192); ZSTORE(1);  VBL(10); COMPUTE(1); EBAR();
    // t=2..13
    {
        int bufS = 1, bufC = 2;
        for (int t = 2; t <= 13; ++t){
            STAGE(bufS, (t+2)*64);
            ZSTORE(t);
            VBL(11);
            COMPUTE(bufC);
            EBAR();
            bufS = (bufS == 2) ? 0 : bufS + 1;
            bufC = (bufC == 2) ? 0 : bufC + 1;
        }
    }
    // t=14 (no stage)
    ZSTORE(14); VBL(7); COMPUTE(2); EBAR();
    // t=15 (no stage)
    ZSTORE(15); VBL(3); COMPUTE(0);

    // epilogue: cos = acc/1024; append to this block's (row, cb) segments
    const float inv = 1.0f / 1024.0f;
    #pragma unroll
    for (int n = 0; n < 4; ++n){
        int gcol = bn + wn*64 + n*16 + lr;
        bool ok = gcol < OUTD;
        #pragma unroll
        for (int m = 0; m < 4; ++m){
            int lr0 = wm*64 + m*16 + lk*4;        // local row (C/D layout)
            #pragma unroll
            for (int r = 0; r < 4; ++r){
                float sc = acc[m][n][r] * inv;
                if (ok && sc > THRESH){
                    int lrow = lr0 + r;
                    int pos = atomicAdd(&lcnt[lrow], 1);   // LDS atomic only
                    if (pos < SEGC)
                        cpk[((size_t)(bm + lrow)*NCB + cb)*SEGC + pos] =
                            ((unsigned long long)(unsigned)gcol << 32) |
                            (unsigned long long)__float_as_uint(sc);
                }
            }
        }
    }
    __syncthreads();                 // drains cpk + trailing zero stores
    if (tid < 128)
        cnt8[(size_t)(bm + tid)*NCB + cb] =
            (unsigned char)min(lcnt[tid], SEGC);
}

// -------- kernel 4: select + f64 refine + scatter (zeroing in gemm) -------
// Determinism: refine SET = {candidates in bins >= bstar} is order-invariant;
// segment contents are set-complete (cap-12 overflow prob ~3e-7/run);
// f64 scores + (score desc, idx asc) sort -> arrival-order independent.
extern "C" __global__ __launch_bounds__(256)
void k_sel(const float* __restrict__ x, const float* __restrict__ w,
           const float* __restrict__ bias,
           const unsigned long long* __restrict__ cpk,
           const unsigned char* __restrict__ cnt8,
           const double* __restrict__ ri64,
           float* __restrict__ out){
    const int row = blockIdx.x, tid = threadIdx.x;
    __shared__ float  xl[DIM];
    __shared__ int    hist[256];
    __shared__ int    bstar, nref;
    __shared__ int    ridx[RCAP];
    __shared__ double rsc[RCAP];
    __shared__ double rdv[RCAP];

    ((float4*)xl)[tid] = ((const float4*)(x + (size_t)row*DIM))[tid];
    hist[tid] = 0;
    if (tid == 0) nref = 0;
    __syncthreads();

    const unsigned char* rc8 = cnt8 + (size_t)row*NCB;
    const unsigned long long* rseg = cpk + (size_t)row*NCB*SEGC;

    // histogram of coarse scores (bins of 7.8e-4 over [0.08, 0.28])
    for (int cb = tid; cb < NCB; cb += 256){
        int c = rc8[cb];
        for (int j = 0; j < c; ++j){
            float s = __uint_as_float((unsigned)(rseg[cb*SEGC + j] & 0xFFFFFFFFu));
            int b = (int)((s - THRESH) * 1280.f);
            b = max(0, min(255, b));
            atomicAdd(&hist[b], 1);
        }
    }
    __syncthreads();
    if (tid == 0){  // smallest bin whose top-cumulative >= NREF
        int cum = 0, b = 255;
        for (; b >= 0; --b){ cum += hist[b]; if (cum >= NREF) break; }
        bstar = b < 0 ? 0 : b;
    }
    __syncthreads();
    const int bs_ = bstar;
    for (int cb = tid; cb < NCB; cb += 256){
        int c = rc8[cb];
        for (int j = 0; j < c; ++j){
            unsigned long long pk = rseg[cb*SEGC + j];
            float s = __uint_as_float((unsigned)(pk & 0xFFFFFFFFu));
            int b = (int)((s - THRESH) * 1280.f);
            b = max(0, min(255, b));
            if (b >= bs_){
                int p = atomicAdd(&nref, 1);
                if (p < RCAP) ridx[p] = (int)(pk >> 32);
            }
        }
    }
    __syncthreads();
    const int nr = min(nref, RCAP);

    // f64 refine: one wave per candidate, float4-vectorized loads
    const int wv = tid >> 6, lane = tid & 63;
    const float4* xl4 = (const float4*)xl;
    for (int q = wv; q < nr; q += 4){
        int col = ridx[q];
        const float4* wr4 = (const float4*)(w + (size_t)col*DIM);
        double s = 0.0;
        #pragma unroll
        for (int u = 0; u < 4; ++u){
            float4 a = xl4[lane + 64*u];
            float4 b = wr4[lane + 64*u];
            s = fma((double)a.x, (double)b.x, s);
            s = fma((double)a.y, (double)b.y, s);
            s = fma((double)a.z, (double)b.z, s);
            s = fma((double)a.w, (double)b.w, s);
        }
        for (int d = 32; d >= 1; d >>= 1) s += __shfl_xor(s, d, 64);
        if (lane == 0){ rdv[q] = s; rsc[q] = s * ri64[col]; }
    }
    __syncthreads();
    if (tid >= nr){ rsc[tid] = -1.0e300; ridx[tid] = 0x7FFFFFFF; rdv[tid] = 0.0; }
    __syncthreads();

    // bitonic sort 256: descending score, ties -> smaller index
    for (int k = 2; k <= RCAP; k <<= 1){
        for (int j = k >> 1; j > 0; j >>= 1){
            int i = tid, ixj = i ^ j;
            if (ixj > i){
                double sa = rsc[i], sb = rsc[ixj];
                int ia = ridx[i], ib = ridx[ixj];
                bool dir = ((i & k) == 0);
                bool pb = (sb > sa) || (sb == sa && ib < ia);
                if (pb == dir){
                    rsc[i] = sb; rsc[ixj] = sa;
                    ridx[i] = ib; ridx[ixj] = ia;
                    double t = rdv[i]; rdv[i] = rdv[ixj]; rdv[ixj] = t;
                }
            }
            __syncthreads();
        }
    }
    if (tid < TOPK && tid < nr){
        int col = ridx[tid];
        out[(size_t)row*OUTD + col] = (float)rdv[tid] + bias[col];
    }
}

// ---------------- launch --------------------------------------------------
extern "C" void kernel_launch(void* const* d_in, const int* in_sizes, int n_in,
                              void* d_out, int out_size, void* d_ws, size_t ws_size,
                              hipStream_t stream){
    const float* x    = (const float*)d_in[0];
    const float* wgt  = (const float*)d_in[1];
    const float* bias = (const float*)d_in[2];
    float* out = (float*)d_out;
    char* ws = (char*)d_ws;

    // workspace carve (~132 MB)
    unsigned char* w8 = (unsigned char*)ws;                         // 51,511,296
    unsigned char* x8 = (unsigned char*)(ws + 51511296);            //  2,097,152
    double* ri64 = (double*)(ws + 53608448);                        //    402,432
    unsigned long long* cpk = (unsigned long long*)(ws + 54010880); // 77,266,944
    unsigned char* cnt8 = (unsigned char*)(ws + 131277824);         //    804,864

    k_init <<<NTOK, 256, 0, stream>>>(x, x8);
    k_wnorm<<<OPAD, 256, 0, stream>>>(wgt, w8, ri64);
    k_gemm <<<NBLK, 256, 0, stream>>>(x8, w8, cpk, cnt8, out);
    k_sel  <<<NTOK, 256, 0, stream>>>(x, wgt, bias, cpk, cnt8, ri64, out);
}

// Round 20
// 489.259 us; speedup vs baseline: 1.6401x; 1.0691x over previous
//
#include <hip/hip_runtime.h>

#define NTOK 2048
#define DIM  1024          // K elements; == bytes for int8
#define OUTD 50257
#define OPAD 50304         // 393*128
#define NCB  393           // column blocks (128 wide)
#define SEGC 12            // slots per (row, colblock) segment
#define TOPK 32
#define RCAP 256           // refine capacity (determinism: nref<=RCAP always)
#define NREF 80            // exact-refine depth (margins vs i8 coarse noise ~8e-4)
#define THRESH 0.08f
#define NBLK 6288          // gemm grid: 16 M-tiles(128) x 393 col-blocks

typedef float f32x4 __attribute__((ext_vector_type(4)));
typedef int   i32x4 __attribute__((ext_vector_type(4)));

// ---- f32 -> int8 (RNE, clamp +-127), pack 4 into dword -------------------
__device__ __forceinline__ unsigned int packq(float a, float b, float c, float d){
    int qa = __float2int_rn(fminf(fmaxf(a, -127.f), 127.f));
    int qb = __float2int_rn(fminf(fmaxf(b, -127.f), 127.f));
    int qc = __float2int_rn(fminf(fmaxf(c, -127.f), 127.f));
    int qd = __float2int_rn(fminf(fmaxf(d, -127.f), 127.f));
    return (unsigned)(qa & 0xFF) | ((unsigned)(qb & 0xFF) << 8) |
           ((unsigned)(qc & 0xFF) << 16) | ((unsigned)(qd & 0xFF) << 24);
}

#define GLDS(gp, lp) __builtin_amdgcn_global_load_lds( \
    (__attribute__((address_space(1))) void*)(gp),     \
    (__attribute__((address_space(3))) void*)(lp), 16, 0, 0)

// ------- kernel 1: x-row L2-normalize, xq = int8(512 * x_hat) -------------
extern "C" __global__ void k_init(const float* __restrict__ x,
                                  unsigned char* __restrict__ xq){
    __shared__ double ls[4];
    const int row = blockIdx.x, t = threadIdx.x;
    float4 v = ((const float4*)(x + (size_t)row * DIM))[t];
    double s = (double)v.x*v.x + (double)v.y*v.y
             + (double)v.z*v.z + (double)v.w*v.w;
    for (int d = 32; d >= 1; d >>= 1) s += __shfl_xor(s, d, 64);
    const int wv = t >> 6, ln = t & 63;
    if (ln == 0) ls[wv] = s;
    __syncthreads();
    double tot = ls[0] + ls[1] + ls[2] + ls[3];
    float sc = (float)(512.0 / fmax(sqrt(tot), 1e-12));
    ((unsigned int*)(xq + (size_t)row * DIM))[t] =
        packq(v.x*sc, v.y*sc, v.z*sc, v.w*sc);
}

// ------- kernel 2: wq = int8(512 * w_hat); ri64 = 1/max(||w||,eps) --------
extern "C" __global__ void k_wnorm(const float* __restrict__ w,
                                   unsigned char* __restrict__ wq,
                                   double* __restrict__ ri64){
    __shared__ double ls[4];
    int r = blockIdx.x, t = threadIdx.x;
    if (r < OUTD){
        float4 v = ((const float4*)(w + (size_t)r * DIM))[t];
        double s = (double)v.x*v.x + (double)v.y*v.y
                 + (double)v.z*v.z + (double)v.w*v.w;
        for (int d = 32; d >= 1; d >>= 1) s += __shfl_xor(s, d, 64);
        int wv = t >> 6, ln = t & 63;
        if (ln == 0) ls[wv] = s;
        __syncthreads();
        double tot = ls[0] + ls[1] + ls[2] + ls[3];
        double ri = 1.0 / fmax(sqrt(tot), 1e-12);
        if (t == 0) ri64[r] = ri;
        float sc = (float)(512.0 * ri);
        ((unsigned int*)(wq + (size_t)r * DIM))[t] =
            packq(v.x*sc, v.y*sc, v.z*sc, v.w*sc);
    } else { // pad rows: zero -> dot 0 -> filtered
        ((unsigned int*)(wq + (size_t)r * DIM))[t] = 0u;
        if (t == 0) ri64[r] = 0.0;
    }
}

// ------ kernel 3: i8 MFMA GEMM, BK=64, RING-3 LDS, depth-2 prefetch -------
// 128x128 tile, 4 waves 2x2 (64x64/wave), 16 K-tiles, mfma_i32_16x16x64_i8.
// LDS per buffer: [4 kchunks][128 rows][16B] = 8KB each A,B; 3 buffers.
// Frag read = full 16B granule per lane (b128): lane (lr,lk) reads
// kchunk=lk, row=...+lr -> bank 4*(row mod 8): rows lr/lr+8 share = 2-way
// FREE (m136). No swizzle needed; producers write linear.
// A/B frag layout (i8 16x16x64): row/col = lane&15, k = (lane>>4)*16+[0..15]
// contiguous — same contiguous-k family verified for fp8 16x16x32 (R7) and
// MX 32x32x64 (R10). C/D: col=lane&15, row=(lane>>4)*4+reg (dtype-indep).
// Per-iter queue UNIFORM {4 GLDS, 1 clamped zero-store}; counted waits:
// ops newer than tile-t's 4 loads = 9 (t=0), 10 (t=1), 11 (t=2..13),
// 7 (t=14), 3 (t=15). Barriers drain lgkmcnt(0).
#define COMPUTE(b) do { \
  i32x4 af_[4], bv_[4]; \
  const char* Ab_ = As[b] + lk*2048; \
  const char* Bb_ = Bs[b] + lk*2048; \
  _Pragma("unroll") \
  for (int m_ = 0; m_ < 4; ++m_) \
    af_[m_] = *(const i32x4*)(Ab_ + (wm*64 + m_*16 + lr)*16); \
  _Pragma("unroll") \
  for (int n_ = 0; n_ < 4; ++n_) \
    bv_[n_] = *(const i32x4*)(Bb_ + (wn*64 + n_*16 + lr)*16); \
  __builtin_amdgcn_s_setprio(1); \
  _Pragma("unroll") \
  for (int m_ = 0; m_ < 4; ++m_) \
    _Pragma("unroll") \
    for (int n_ = 0; n_ < 4; ++n_) \
      acc[m_][n_] = __builtin_amdgcn_mfma_i32_16x16x64_i8( \
                        af_[m_], bv_[n_], acc[m_][n_], 0, 0, 0); \
  __builtin_amdgcn_s_setprio(0); \
} while(0)

#define STAGE(b, K0) do { \
  GLDS(xq + offA0 + (K0), As[b] + tid*16); \
  GLDS(xq + offA0 + 32 + (K0), As[b] + (tid+256)*16); \
  GLDS(wq + offB0 + (K0), Bs[b] + tid*16); \
  GLDS(wq + offB0 + 32 + (K0), Bs[b] + (tid+256)*16); \
} while(0)

#define ZSTORE(IT) do { \
  size_t zi_ = ((size_t)orig*16 + (IT))*256 + tid; \
  if (zi_ >= n4) zi_ = n4 - 1;     /* idempotent; keeps queue uniform */ \
  ((float4*)out)[zi_] = z4; \
} while(0)

#define VBL(N) do { \
  asm volatile("s_waitcnt vmcnt(" #N ") lgkmcnt(0)" ::: "memory"); \
  __builtin_amdgcn_s_barrier(); \
  asm volatile("" ::: "memory"); \
} while(0)

#define EBAR() do { \
  __builtin_amdgcn_s_barrier(); \
  asm volatile("" ::: "memory"); \
} while(0)

extern "C" __global__ __launch_bounds__(256)
void k_gemm(const unsigned char* __restrict__ xq,
            const unsigned char* __restrict__ wq,
            unsigned long long* __restrict__ cpk,
            unsigned char* __restrict__ cnt8,
            float* __restrict__ out){
    __shared__ __align__(16) char As[3][8192];
    __shared__ __align__(16) char Bs[3][8192];
    __shared__ int lcnt[128];
    const int tid = threadIdx.x;

    // bijective chunked XCD remap: 6288 = 8*786
    const int orig  = blockIdx.x;
    const int newid = (orig & 7) * 786 + (orig >> 3);
    const int bm    = (newid & 15) * 128;
    const int cb    = newid >> 4;               // column block 0..392
    const int bn    = cb * 128;

    const int wv = tid >> 6, lane = tid & 63;
    const int wm = wv >> 1,  wn = wv & 1;       // 2x2 waves, 64x64 each
    const int lr = lane & 15, lk = lane >> 4;

    if (tid < 128) lcnt[tid] = 0;

    i32x4 zi4 = {0, 0, 0, 0};
    i32x4 acc[4][4];
    for (int m = 0; m < 4; ++m) for (int n = 0; n < 4; ++n) acc[m][n] = zi4;

    // staging map: 512 16B segs per matrix per K-tile; 2 each (A,B)/thread.
    // seg = kchunk*128 + row; thread t -> segs t (kc 0-1) and t+256 (kc 2-3).
    // dst = seg*16: wave-contiguous (m104-safe).
    const size_t offA0 = (size_t)(bm + (tid & 127))*DIM + (tid >> 7)*16;
    const size_t offB0 = (size_t)(bn + (tid & 127))*DIM + (tid >> 7)*16;

    const size_t n4 = (size_t)NTOK * OUTD / 4;  // 25,731,584
    const float4 z4 = make_float4(0.f, 0.f, 0.f, 0.f);

    // ---- ring-3 pipeline over 16 K-tiles (BK=64) ----
    STAGE(0, 0);
    STAGE(1, 64);
    // t=0
    STAGE(2, 128); ZSTORE(0);  VBL(9);  COMPUTE(0); EBAR();
    // t=1
    STAGE(0, 192); ZSTORE(1);  VBL(10); COMPUTE(1); EBAR();
    // t=2..13
    {
        int bufS = 1, bufC = 2;
        for (int t = 2; t <= 13; ++t){
            STAGE(bufS, (t+2)*64);
            ZSTORE(t);
            VBL(11);
            COMPUTE(bufC);
            EBAR();
            bufS = (bufS == 2) ? 0 : bufS + 1;
            bufC = (bufC == 2) ? 0 : bufC + 1;
        }
    }
    // t=14 (no stage)
    ZSTORE(14); VBL(7); COMPUTE(2); EBAR();
    // t=15 (no stage)
    ZSTORE(15); VBL(3); COMPUTE(0);

    // epilogue: cos ~= dot/(512*512); append to (row, cb) segments
    const float inv = 1.0f / 262144.0f;
    #pragma unroll
    for (int n = 0; n < 4; ++n){
        int gcol = bn + wn*64 + n*16 + lr;
        bool ok = gcol < OUTD;
        #pragma unroll
        for (int m = 0; m < 4; ++m){
            int lr0 = wm*64 + m*16 + lk*4;        // local row (C/D layout)
            #pragma unroll
            for (int r = 0; r < 4; ++r){
                float sc = (float)acc[m][n][r] * inv;
                if (ok && sc > THRESH){
                    int lrow = lr0 + r;
                    int pos = atomicAdd(&lcnt[lrow], 1);   // LDS atomic only
                    if (pos < SEGC)
                        cpk[((size_t)(bm + lrow)*NCB + cb)*SEGC + pos] =
                            ((unsigned long long)(unsigned)gcol << 32) |
                            (unsigned long long)__float_as_uint(sc);
                }
            }
        }
    }
    __syncthreads();                 // drains cpk + trailing zero stores
    if (tid < 128)
        cnt8[(size_t)(bm + tid)*NCB + cb] =
            (unsigned char)min(lcnt[tid], SEGC);
}

// -------- kernel 4: select + f64 refine + scatter (zeroing in gemm) -------
// Determinism: refine SET = {candidates in bins >= bstar} is order-invariant;
// segment contents are set-complete (cap-12 overflow prob ~3e-7/run);
// f64 scores + (score desc, idx asc) sort -> arrival-order independent.
extern "C" __global__ __launch_bounds__(256)
void k_sel(const float* __restrict__ x, const float* __restrict__ w,
           const float* __restrict__ bias,
           const unsigned long long* __restrict__ cpk,
           const unsigned char* __restrict__ cnt8,
           const double* __restrict__ ri64,
           float* __restrict__ out){
    const int row = blockIdx.x, tid = threadIdx.x;
    __shared__ float  xl[DIM];
    __shared__ int    hist[256];
    __shared__ int    bstar, nref;
    __shared__ int    ridx[RCAP];
    __shared__ double rsc[RCAP];
    __shared__ double rdv[RCAP];

    ((float4*)xl)[tid] = ((const float4*)(x + (size_t)row*DIM))[tid];
    hist[tid] = 0;
    if (tid == 0) nref = 0;
    __syncthreads();

    const unsigned char* rc8 = cnt8 + (size_t)row*NCB;
    const unsigned long long* rseg = cpk + (size_t)row*NCB*SEGC;

    // histogram of coarse scores (bins of 7.8e-4 over [0.08, 0.28])
    for (int cb = tid; cb < NCB; cb += 256){
        int c = rc8[cb];
        for (int j = 0; j < c; ++j){
            float s = __uint_as_float((unsigned)(rseg[cb*SEGC + j] & 0xFFFFFFFFu));
            int b = (int)((s - THRESH) * 1280.f);
            b = max(0, min(255, b));
            atomicAdd(&hist[b], 1);
        }
    }
    __syncthreads();
    if (tid == 0){  // smallest bin whose top-cumulative >= NREF
        int cum = 0, b = 255;
        for (; b >= 0; --b){ cum += hist[b]; if (cum >= NREF) break; }
        bstar = b < 0 ? 0 : b;
    }
    __syncthreads();
    const int bs_ = bstar;
    for (int cb = tid; cb < NCB; cb += 256){
        int c = rc8[cb];
        for (int j = 0; j < c; ++j){
            unsigned long long pk = rseg[cb*SEGC + j];
            float s = __uint_as_float((unsigned)(pk & 0xFFFFFFFFu));
            int b = (int)((s - THRESH) * 1280.f);
            b = max(0, min(255, b));
            if (b >= bs_){
                int p = atomicAdd(&nref, 1);
                if (p < RCAP) ridx[p] = (int)(pk >> 32);
            }
        }
    }
    __syncthreads();
    const int nr = min(nref, RCAP);

    // f64 refine: one wave per candidate, float4-vectorized loads
    const int wv = tid >> 6, lane = tid & 63;
    const float4* xl4 = (const float4*)xl;
    for (int q = wv; q < nr; q += 4){
        int col = ridx[q];
        const float4* wr4 = (const float4*)(w + (size_t)col*DIM);
        double s = 0.0;
        #pragma unroll
        for (int u = 0; u < 4; ++u){
            float4 a = xl4[lane + 64*u];
            float4 b = wr4[lane + 64*u];
            s = fma((double)a.x, (double)b.x, s);
            s = fma((double)a.y, (double)b.y, s);
            s = fma((double)a.z, (double)b.z, s);
            s = fma((double)a.w, (double)b.w, s);
        }
        for (int d = 32; d >= 1; d >>= 1) s += __shfl_xor(s, d, 64);
        if (lane == 0){ rdv[q] = s; rsc[q] = s * ri64[col]; }
    }
    __syncthreads();
    if (tid >= nr){ rsc[tid] = -1.0e300; ridx[tid] = 0x7FFFFFFF; rdv[tid] = 0.0; }
    __syncthreads();

    // bitonic sort 256: descending score, ties -> smaller index
    for (int k = 2; k <= RCAP; k <<= 1){
        for (int j = k >> 1; j > 0; j >>= 1){
            int i = tid, ixj = i ^ j;
            if (ixj > i){
                double sa = rsc[i], sb = rsc[ixj];
                int ia = ridx[i], ib = ridx[ixj];
                bool dir = ((i & k) == 0);
                bool pb = (sb > sa) || (sb == sa && ib < ia);
                if (pb == dir){
                    rsc[i] = sb; rsc[ixj] = sa;
                    ridx[i] = ib; ridx[ixj] = ia;
                    double t = rdv[i]; rdv[i] = rdv[ixj]; rdv[ixj] = t;
                }
            }
            __syncthreads();
        }
    }
    if (tid < TOPK && tid < nr){
        int col = ridx[tid];
        out[(size_t)row*OUTD + col] = (float)rdv[tid] + bias[col];
    }
}

// ---------------- launch --------------------------------------------------
extern "C" void kernel_launch(void* const* d_in, const int* in_sizes, int n_in,
                              void* d_out, int out_size, void* d_ws, size_t ws_size,
                              hipStream_t stream){
    const float* x    = (const float*)d_in[0];
    const float* wgt  = (const float*)d_in[1];
    const float* bias = (const float*)d_in[2];
    float* out = (float*)d_out;
    char* ws = (char*)d_ws;

    // workspace carve (~132 MB)
    unsigned char* wq = (unsigned char*)ws;                         // 51,511,296
    unsigned char* xq = (unsigned char*)(ws + 51511296);            //  2,097,152
    double* ri64 = (double*)(ws + 53608448);                        //    402,432
    unsigned long long* cpk = (unsigned long long*)(ws + 54010880); // 77,266,944
    unsigned char* cnt8 = (unsigned char*)(ws + 131277824);         //    804,864

    k_init <<<NTOK, 256, 0, stream>>>(x, xq);
    k_wnorm<<<OPAD, 256, 0, stream>>>(wgt, wq, ri64);
    k_gemm <<<NBLK, 256, 0, stream>>>(xq, wq, cpk, cnt8, out);
    k_sel  <<<NTOK, 256, 0, stream>>>(x, wgt, bias, cpk, cnt8, ri64, out);
}

// Round 21
// 480.303 us; speedup vs baseline: 1.6707x; 1.0186x over previous
//
#include <hip/hip_runtime.h>

#define NTOK 2048
#define DIM  1024          // K elements; == bytes for int8
#define OUTD 50257
#define OPAD 50304         // 393*128
#define NCB  393           // column blocks (128 wide)
#define SEGC 12            // slots per (row, colblock) segment
#define TOPK 32
#define RCAP 256           // refine capacity (determinism: nref<=RCAP always)
#define NREF 80            // exact-refine depth (margins vs i8 coarse noise ~8e-4)
#define THRESH 0.08f
#define NBLK 6288          // gemm grid: 16 M-tiles(128) x 393 col-blocks

typedef float f32x4 __attribute__((ext_vector_type(4)));
typedef int   i32x4 __attribute__((ext_vector_type(4)));

// ---- f32 -> int8 (RNE, clamp +-127), pack 4 into dword -------------------
__device__ __forceinline__ unsigned int packq(float a, float b, float c, float d){
    int qa = __float2int_rn(fminf(fmaxf(a, -127.f), 127.f));
    int qb = __float2int_rn(fminf(fmaxf(b, -127.f), 127.f));
    int qc = __float2int_rn(fminf(fmaxf(c, -127.f), 127.f));
    int qd = __float2int_rn(fminf(fmaxf(d, -127.f), 127.f));
    return (unsigned)(qa & 0xFF) | ((unsigned)(qb & 0xFF) << 8) |
           ((unsigned)(qc & 0xFF) << 16) | ((unsigned)(qd & 0xFF) << 24);
}

#define GLDS(gp, lp) __builtin_amdgcn_global_load_lds( \
    (__attribute__((address_space(1))) void*)(gp),     \
    (__attribute__((address_space(3))) void*)(lp), 16, 0, 0)

// ------- kernel 1: x-row L2-norm -> int8(512*x_hat); 1 wave/row, no barriers
extern "C" __global__ void k_init(const float* __restrict__ x,
                                  unsigned char* __restrict__ xq){
    const int row  = blockIdx.x * 4 + (threadIdx.x >> 6);
    const int lane = threadIdx.x & 63;
    const float4* xr = (const float4*)(x + (size_t)row * DIM);
    float4 v0 = xr[lane], v1 = xr[lane + 64], v2 = xr[lane + 128], v3 = xr[lane + 192];
    double s = (double)v0.x*v0.x + (double)v0.y*v0.y + (double)v0.z*v0.z + (double)v0.w*v0.w
             + (double)v1.x*v1.x + (double)v1.y*v1.y + (double)v1.z*v1.z + (double)v1.w*v1.w
             + (double)v2.x*v2.x + (double)v2.y*v2.y + (double)v2.z*v2.z + (double)v2.w*v2.w
             + (double)v3.x*v3.x + (double)v3.y*v3.y + (double)v3.z*v3.z + (double)v3.w*v3.w;
    for (int d = 32; d >= 1; d >>= 1) s += __shfl_xor(s, d, 64);
    float sc = (float)(512.0 / fmax(sqrt(s), 1e-12));
    unsigned int* o = (unsigned int*)(xq + (size_t)row * DIM);
    o[lane]       = packq(v0.x*sc, v0.y*sc, v0.z*sc, v0.w*sc);
    o[lane + 64]  = packq(v1.x*sc, v1.y*sc, v1.z*sc, v1.w*sc);
    o[lane + 128] = packq(v2.x*sc, v2.y*sc, v2.z*sc, v2.w*sc);
    o[lane + 192] = packq(v3.x*sc, v3.y*sc, v3.z*sc, v3.w*sc);
}

// ------- kernel 2: wq = int8(512*w_hat); ri64 = 1/max(||w||,eps); 1 wave/row
extern "C" __global__ void k_wnorm(const float* __restrict__ w,
                                   unsigned char* __restrict__ wq,
                                   double* __restrict__ ri64){
    const int row  = blockIdx.x * 4 + (threadIdx.x >> 6);
    const int lane = threadIdx.x & 63;
    unsigned int* o = (unsigned int*)(wq + (size_t)row * DIM);
    if (row < OUTD){
        const float4* wr = (const float4*)(w + (size_t)row * DIM);
        float4 v0 = wr[lane], v1 = wr[lane + 64], v2 = wr[lane + 128], v3 = wr[lane + 192];
        double s = (double)v0.x*v0.x + (double)v0.y*v0.y + (double)v0.z*v0.z + (double)v0.w*v0.w
                 + (double)v1.x*v1.x + (double)v1.y*v1.y + (double)v1.z*v1.z + (double)v1.w*v1.w
                 + (double)v2.x*v2.x + (double)v2.y*v2.y + (double)v2.z*v2.z + (double)v2.w*v2.w
                 + (double)v3.x*v3.x + (double)v3.y*v3.y + (double)v3.z*v3.z + (double)v3.w*v3.w;
        for (int d = 32; d >= 1; d >>= 1) s += __shfl_xor(s, d, 64);
        double ri = 1.0 / fmax(sqrt(s), 1e-12);
        if (lane == 0) ri64[row] = ri;
        float sc = (float)(512.0 * ri);
        o[lane]       = packq(v0.x*sc, v0.y*sc, v0.z*sc, v0.w*sc);
        o[lane + 64]  = packq(v1.x*sc, v1.y*sc, v1.z*sc, v1.w*sc);
        o[lane + 128] = packq(v2.x*sc, v2.y*sc, v2.z*sc, v2.w*sc);
        o[lane + 192] = packq(v3.x*sc, v3.y*sc, v3.z*sc, v3.w*sc);
    } else { // pad rows: zero -> dot 0 -> filtered
        o[lane] = 0u; o[lane + 64] = 0u; o[lane + 128] = 0u; o[lane + 192] = 0u;
        if (lane == 0) ri64[row] = 0.0;
    }
}

// ------ kernel 3: i8 MFMA GEMM, BK=64, RING-3 LDS, depth-2 prefetch -------
// [R20 verbatim — proven best; K-loop plateau accepted: dur invariant across
//  dbuf/ring/tile/swizzle/dtype (303/318/299/294/291).]
#define COMPUTE(b) do { \
  i32x4 af_[4], bv_[4]; \
  const char* Ab_ = As[b] + lk*2048; \
  const char* Bb_ = Bs[b] + lk*2048; \
  _Pragma("unroll") \
  for (int m_ = 0; m_ < 4; ++m_) \
    af_[m_] = *(const i32x4*)(Ab_ + (wm*64 + m_*16 + lr)*16); \
  _Pragma("unroll") \
  for (int n_ = 0; n_ < 4; ++n_) \
    bv_[n_] = *(const i32x4*)(Bb_ + (wn*64 + n_*16 + lr)*16); \
  __builtin_amdgcn_s_setprio(1); \
  _Pragma("unroll") \
  for (int m_ = 0; m_ < 4; ++m_) \
    _Pragma("unroll") \
    for (int n_ = 0; n_ < 4; ++n_) \
      acc[m_][n_] = __builtin_amdgcn_mfma_i32_16x16x64_i8( \
                        af_[m_], bv_[n_], acc[m_][n_], 0, 0, 0); \
  __builtin_amdgcn_s_setprio(0); \
} while(0)

#define STAGE(b, K0) do { \
  GLDS(xq + offA0 + (K0), As[b] + tid*16); \
  GLDS(xq + offA0 + 32 + (K0), As[b] + (tid+256)*16); \
  GLDS(wq + offB0 + (K0), Bs[b] + tid*16); \
  GLDS(wq + offB0 + 32 + (K0), Bs[b] + (tid+256)*16); \
} while(0)

#define ZSTORE(IT) do { \
  size_t zi_ = ((size_t)orig*16 + (IT))*256 + tid; \
  if (zi_ >= n4) zi_ = n4 - 1;     /* idempotent; keeps queue uniform */ \
  ((float4*)out)[zi_] = z4; \
} while(0)

#define VBL(N) do { \
  asm volatile("s_waitcnt vmcnt(" #N ") lgkmcnt(0)" ::: "memory"); \
  __builtin_amdgcn_s_barrier(); \
  asm volatile("" ::: "memory"); \
} while(0)

#define EBAR() do { \
  __builtin_amdgcn_s_barrier(); \
  asm volatile("" ::: "memory"); \
} while(0)

extern "C" __global__ __launch_bounds__(256)
void k_gemm(const unsigned char* __restrict__ xq,
            const unsigned char* __restrict__ wq,
            unsigned long long* __restrict__ cpk,
            unsigned char* __restrict__ cnt8,
            float* __restrict__ out){
    __shared__ __align__(16) char As[3][8192];
    __shared__ __align__(16) char Bs[3][8192];
    __shared__ int lcnt[128];
    const int tid = threadIdx.x;

    // bijective chunked XCD remap: 6288 = 8*786
    const int orig  = blockIdx.x;
    const int newid = (orig & 7) * 786 + (orig >> 3);
    const int bm    = (newid & 15) * 128;
    const int cb    = newid >> 4;               // column block 0..392
    const int bn    = cb * 128;

    const int wv = tid >> 6, lane = tid & 63;
    const int wm = wv >> 1,  wn = wv & 1;       // 2x2 waves, 64x64 each
    const int lr = lane & 15, lk = lane >> 4;

    if (tid < 128) lcnt[tid] = 0;

    i32x4 zi4 = {0, 0, 0, 0};
    i32x4 acc[4][4];
    for (int m = 0; m < 4; ++m) for (int n = 0; n < 4; ++n) acc[m][n] = zi4;

    const size_t offA0 = (size_t)(bm + (tid & 127))*DIM + (tid >> 7)*16;
    const size_t offB0 = (size_t)(bn + (tid & 127))*DIM + (tid >> 7)*16;

    const size_t n4 = (size_t)NTOK * OUTD / 4;  // 25,731,584
    const float4 z4 = make_float4(0.f, 0.f, 0.f, 0.f);

    // ---- ring-3 pipeline over 16 K-tiles (BK=64) ----
    STAGE(0, 0);
    STAGE(1, 64);
    STAGE(2, 128); ZSTORE(0);  VBL(9);  COMPUTE(0); EBAR();
    STAGE(0, 192); ZSTORE(1);  VBL(10); COMPUTE(1); EBAR();
    {
        int bufS = 1, bufC = 2;
        for (int t = 2; t <= 13; ++t){
            STAGE(bufS, (t+2)*64);
            ZSTORE(t);
            VBL(11);
            COMPUTE(bufC);
            EBAR();
            bufS = (bufS == 2) ? 0 : bufS + 1;
            bufC = (bufC == 2) ? 0 : bufC + 1;
        }
    }
    ZSTORE(14); VBL(7); COMPUTE(2); EBAR();
    ZSTORE(15); VBL(3); COMPUTE(0);

    // epilogue: cos ~= dot/(512*512); append to (row, cb) segments
    const float inv = 1.0f / 262144.0f;
    #pragma unroll
    for (int n = 0; n < 4; ++n){
        int gcol = bn + wn*64 + n*16 + lr;
        bool ok = gcol < OUTD;
        #pragma unroll
        for (int m = 0; m < 4; ++m){
            int lr0 = wm*64 + m*16 + lk*4;        // local row (C/D layout)
            #pragma unroll
            for (int r = 0; r < 4; ++r){
                float sc = (float)acc[m][n][r] * inv;
                if (ok && sc > THRESH){
                    int lrow = lr0 + r;
                    int pos = atomicAdd(&lcnt[lrow], 1);   // LDS atomic only
                    if (pos < SEGC)
                        cpk[((size_t)(bm + lrow)*NCB + cb)*SEGC + pos] =
                            ((unsigned long long)(unsigned)gcol << 32) |
                            (unsigned long long)__float_as_uint(sc);
                }
            }
        }
    }
    __syncthreads();                 // drains cpk + trailing zero stores
    if (tid < 128)
        cnt8[(size_t)(bm + tid)*NCB + cb] =
            (unsigned char)min(lcnt[tid], SEGC);
}

// -------- kernel 4: select + f64 refine + scatter (zeroing in gemm) -------
// Determinism: refine SET = {candidates in bins >= bstar} is order-invariant;
// segment contents are set-complete (cap-12 overflow prob ~3e-7/run);
// f64 scores + (score desc, idx asc) sort -> arrival-order independent.
extern "C" __global__ __launch_bounds__(256)
void k_sel(const float* __restrict__ x, const float* __restrict__ w,
           const float* __restrict__ bias,
           const unsigned long long* __restrict__ cpk,
           const unsigned char* __restrict__ cnt8,
           const double* __restrict__ ri64,
           float* __restrict__ out){
    const int row = blockIdx.x, tid = threadIdx.x;
    __shared__ float  xl[DIM];
    __shared__ int    hist[256];
    __shared__ int    bstar, nref;
    __shared__ int    ridx[RCAP];
    __shared__ double rsc[RCAP];
    __shared__ double rdv[RCAP];

    ((float4*)xl)[tid] = ((const float4*)(x + (size_t)row*DIM))[tid];
    hist[tid] = 0;
    if (tid == 0) nref = 0;
    __syncthreads();

    const unsigned char* rc8 = cnt8 + (size_t)row*NCB;
    const unsigned long long* rseg = cpk + (size_t)row*NCB*SEGC;

    // histogram of coarse scores (bins of 7.8e-4 over [0.08, 0.28])
    for (int cb = tid; cb < NCB; cb += 256){
        int c = rc8[cb];
        for (int j = 0; j < c; ++j){
            float s = __uint_as_float((unsigned)(rseg[cb*SEGC + j] & 0xFFFFFFFFu));
            int b = (int)((s - THRESH) * 1280.f);
            b = max(0, min(255, b));
            atomicAdd(&hist[b], 1);
        }
    }
    __syncthreads();
    if (tid == 0){  // smallest bin whose top-cumulative >= NREF
        int cum = 0, b = 255;
        for (; b >= 0; --b){ cum += hist[b]; if (cum >= NREF) break; }
        bstar = b < 0 ? 0 : b;
    }
    __syncthreads();
    const int bs_ = bstar;
    for (int cb = tid; cb < NCB; cb += 256){
        int c = rc8[cb];
        for (int j = 0; j < c; ++j){
            unsigned long long pk = rseg[cb*SEGC + j];
            float s = __uint_as_float((unsigned)(pk & 0xFFFFFFFFu));
            int b = (int)((s - THRESH) * 1280.f);
            b = max(0, min(255, b));
            if (b >= bs_){
                int p = atomicAdd(&nref, 1);
                if (p < RCAP) ridx[p] = (int)(pk >> 32);
            }
        }
    }
    __syncthreads();
    const int nr = min(nref, RCAP);

    // f64 refine: one wave per candidate, float4-vectorized loads
    const int wv = tid >> 6, lane = tid & 63;
    const float4* xl4 = (const float4*)xl;
    for (int q = wv; q < nr; q += 4){
        int col = ridx[q];
        const float4* wr4 = (const float4*)(w + (size_t)col*DIM);
        double s = 0.0;
        #pragma unroll
        for (int u = 0; u < 4; ++u){
            float4 a = xl4[lane + 64*u];
            float4 b = wr4[lane + 64*u];
            s = fma((double)a.x, (double)b.x, s);
            s = fma((double)a.y, (double)b.y, s);
            s = fma((double)a.z, (double)b.z, s);
            s = fma((double)a.w, (double)b.w, s);
        }
        for (int d = 32; d >= 1; d >>= 1) s += __shfl_xor(s, d, 64);
        if (lane == 0){ rdv[q] = s; rsc[q] = s * ri64[col]; }
    }
    __syncthreads();
    if (tid >= nr){ rsc[tid] = -1.0e300; ridx[tid] = 0x7FFFFFFF; rdv[tid] = 0.0; }
    __syncthreads();

    // bitonic sort 256: descending score, ties -> smaller index
    for (int k = 2; k <= RCAP; k <<= 1){
        for (int j = k >> 1; j > 0; j >>= 1){
            int i = tid, ixj = i ^ j;
            if (ixj > i){
                double sa = rsc[i], sb = rsc[ixj];
                int ia = ridx[i], ib = ridx[ixj];
                bool dir = ((i & k) == 0);
                bool pb = (sb > sa) || (sb == sa && ib < ia);
                if (pb == dir){
                    rsc[i] = sb; rsc[ixj] = sa;
                    ridx[i] = ib; ridx[ixj] = ia;
                    double t = rdv[i]; rdv[i] = rdv[ixj]; rdv[ixj] = t;
                }
            }
            __syncthreads();
        }
    }
    if (tid < TOPK && tid < nr){
        int col = ridx[tid];
        out[(size_t)row*OUTD + col] = (float)rdv[tid] + bias[col];
    }
}

// ---------------- launch --------------------------------------------------
extern "C" void kernel_launch(void* const* d_in, const int* in_sizes, int n_in,
                              void* d_out, int out_size, void* d_ws, size_t ws_size,
                              hipStream_t stream){
    const float* x    = (const float*)d_in[0];
    const float* wgt  = (const float*)d_in[1];
    const float* bias = (const float*)d_in[2];
    float* out = (float*)d_out;
    char* ws = (char*)d_ws;

    // workspace carve (~132 MB)
    unsigned char* wq = (unsigned char*)ws;                         // 51,511,296
    unsigned char* xq = (unsigned char*)(ws + 51511296);            //  2,097,152
    double* ri64 = (double*)(ws + 53608448);                        //    402,432
    unsigned long long* cpk = (unsigned long long*)(ws + 54010880); // 77,266,944
    unsigned char* cnt8 = (unsigned char*)(ws + 131277824);         //    804,864

    k_init <<<NTOK/4, 256, 0, stream>>>(x, xq);
    k_wnorm<<<OPAD/4, 256, 0, stream>>>(wgt, wq, ri64);
    k_gemm <<<NBLK, 256, 0, stream>>>(xq, wq, cpk, cnt8, out);
    k_sel  <<<NTOK, 256, 0, stream>>>(x, wgt, bias, cpk, cnt8, ri64, out);
}

// Round 22
// 443.013 us; speedup vs baseline: 1.8113x; 1.0842x over previous
//
#include <hip/hip_runtime.h>

#define NTOK 2048
#define DIM  1024          // K elements; == bytes for int8
#define OUTD 50257
#define OPAD 50304         // 393*128
#define NCB  393           // column blocks (128 wide)
#define SEGC 12            // slots per (row, colblock) segment
#define TOPK 32
#define RCAP 256           // refine capacity (determinism: nref<=RCAP always)
#define CCAP 768           // LDS candidate cache (mean 261/row, 31 sigma)
#define NREF 64            // exact-refine depth (11 sigma vs i8 coarse noise)
#define THRESH 0.08f
#define NBLK 6288          // gemm grid: 16 M-tiles(128) x 393 col-blocks

typedef float f32x4 __attribute__((ext_vector_type(4)));
typedef int   i32x4 __attribute__((ext_vector_type(4)));

// ---- f32 -> int8 (RNE, clamp +-127), pack 4 into dword -------------------
__device__ __forceinline__ unsigned int packq(float a, float b, float c, float d){
    int qa = __float2int_rn(fminf(fmaxf(a, -127.f), 127.f));
    int qb = __float2int_rn(fminf(fmaxf(b, -127.f), 127.f));
    int qc = __float2int_rn(fminf(fmaxf(c, -127.f), 127.f));
    int qd = __float2int_rn(fminf(fmaxf(d, -127.f), 127.f));
    return (unsigned)(qa & 0xFF) | ((unsigned)(qb & 0xFF) << 8) |
           ((unsigned)(qc & 0xFF) << 16) | ((unsigned)(qd & 0xFF) << 24);
}

#define GLDS(gp, lp) __builtin_amdgcn_global_load_lds( \
    (__attribute__((address_space(1))) void*)(gp),     \
    (__attribute__((address_space(3))) void*)(lp), 16, 0, 0)

// ------- kernel 1: x-row L2-norm -> int8(512*x_hat); 1 wave/row, no barriers
extern "C" __global__ void k_init(const float* __restrict__ x,
                                  unsigned char* __restrict__ xq){
    const int row  = blockIdx.x * 4 + (threadIdx.x >> 6);
    const int lane = threadIdx.x & 63;
    const float4* xr = (const float4*)(x + (size_t)row * DIM);
    float4 v0 = xr[lane], v1 = xr[lane + 64], v2 = xr[lane + 128], v3 = xr[lane + 192];
    double s = (double)v0.x*v0.x + (double)v0.y*v0.y + (double)v0.z*v0.z + (double)v0.w*v0.w
             + (double)v1.x*v1.x + (double)v1.y*v1.y + (double)v1.z*v1.z + (double)v1.w*v1.w
             + (double)v2.x*v2.x + (double)v2.y*v2.y + (double)v2.z*v2.z + (double)v2.w*v2.w
             + (double)v3.x*v3.x + (double)v3.y*v3.y + (double)v3.z*v3.z + (double)v3.w*v3.w;
    for (int d = 32; d >= 1; d >>= 1) s += __shfl_xor(s, d, 64);
    float sc = (float)(512.0 / fmax(sqrt(s), 1e-12));
    unsigned int* o = (unsigned int*)(xq + (size_t)row * DIM);
    o[lane]       = packq(v0.x*sc, v0.y*sc, v0.z*sc, v0.w*sc);
    o[lane + 64]  = packq(v1.x*sc, v1.y*sc, v1.z*sc, v1.w*sc);
    o[lane + 128] = packq(v2.x*sc, v2.y*sc, v2.z*sc, v2.w*sc);
    o[lane + 192] = packq(v3.x*sc, v3.y*sc, v3.z*sc, v3.w*sc);
}

// ------- kernel 2: wq = int8(512*w_hat); ri64 = 1/max(||w||,eps); 1 wave/row
extern "C" __global__ void k_wnorm(const float* __restrict__ w,
                                   unsigned char* __restrict__ wq,
                                   double* __restrict__ ri64){
    const int row  = blockIdx.x * 4 + (threadIdx.x >> 6);
    const int lane = threadIdx.x & 63;
    unsigned int* o = (unsigned int*)(wq + (size_t)row * DIM);
    if (row < OUTD){
        const float4* wr = (const float4*)(w + (size_t)row * DIM);
        float4 v0 = wr[lane], v1 = wr[lane + 64], v2 = wr[lane + 128], v3 = wr[lane + 192];
        double s = (double)v0.x*v0.x + (double)v0.y*v0.y + (double)v0.z*v0.z + (double)v0.w*v0.w
                 + (double)v1.x*v1.x + (double)v1.y*v1.y + (double)v1.z*v1.z + (double)v1.w*v1.w
                 + (double)v2.x*v2.x + (double)v2.y*v2.y + (double)v2.z*v2.z + (double)v2.w*v2.w
                 + (double)v3.x*v3.x + (double)v3.y*v3.y + (double)v3.z*v3.z + (double)v3.w*v3.w;
        for (int d = 32; d >= 1; d >>= 1) s += __shfl_xor(s, d, 64);
        double ri = 1.0 / fmax(sqrt(s), 1e-12);
        if (lane == 0) ri64[row] = ri;
        float sc = (float)(512.0 * ri);
        o[lane]       = packq(v0.x*sc, v0.y*sc, v0.z*sc, v0.w*sc);
        o[lane + 64]  = packq(v1.x*sc, v1.y*sc, v1.z*sc, v1.w*sc);
        o[lane + 128] = packq(v2.x*sc, v2.y*sc, v2.z*sc, v2.w*sc);
        o[lane + 192] = packq(v3.x*sc, v3.y*sc, v3.z*sc, v3.w*sc);
    } else { // pad rows: zero -> dot 0 -> filtered
        o[lane] = 0u; o[lane + 64] = 0u; o[lane + 128] = 0u; o[lane + 192] = 0u;
        if (lane == 0) ri64[row] = 0.0;
    }
}

// ------ kernel 3: i8 MFMA GEMM, BK=64, RING-3 LDS, depth-2 prefetch -------
// [R20 verbatim — proven best; K-loop plateau accepted: dur invariant across
//  dbuf/ring/tile/swizzle/dtype (303/318/299/294/291).]
#define COMPUTE(b) do { \
  i32x4 af_[4], bv_[4]; \
  const char* Ab_ = As[b] + lk*2048; \
  const char* Bb_ = Bs[b] + lk*2048; \
  _Pragma("unroll") \
  for (int m_ = 0; m_ < 4; ++m_) \
    af_[m_] = *(const i32x4*)(Ab_ + (wm*64 + m_*16 + lr)*16); \
  _Pragma("unroll") \
  for (int n_ = 0; n_ < 4; ++n_) \
    bv_[n_] = *(const i32x4*)(Bb_ + (wn*64 + n_*16 + lr)*16); \
  __builtin_amdgcn_s_setprio(1); \
  _Pragma("unroll") \
  for (int m_ = 0; m_ < 4; ++m_) \
    _Pragma("unroll") \
    for (int n_ = 0; n_ < 4; ++n_) \
      acc[m_][n_] = __builtin_amdgcn_mfma_i32_16x16x64_i8( \
                        af_[m_], bv_[n_], acc[m_][n_], 0, 0, 0); \
  __builtin_amdgcn_s_setprio(0); \
} while(0)

#define STAGE(b, K0) do { \
  GLDS(xq + offA0 + (K0), As[b] + tid*16); \
  GLDS(xq + offA0 + 32 + (K0), As[b] + (tid+256)*16); \
  GLDS(wq + offB0 + (K0), Bs[b] + tid*16); \
  GLDS(wq + offB0 + 32 + (K0), Bs[b] + (tid+256)*16); \
} while(0)

#define ZSTORE(IT) do { \
  size_t zi_ = ((size_t)orig*16 + (IT))*256 + tid; \
  if (zi_ >= n4) zi_ = n4 - 1;     /* idempotent; keeps queue uniform */ \
  ((float4*)out)[zi_] = z4; \
} while(0)

#define VBL(N) do { \
  asm volatile("s_waitcnt vmcnt(" #N ") lgkmcnt(0)" ::: "memory"); \
  __builtin_amdgcn_s_barrier(); \
  asm volatile("" ::: "memory"); \
} while(0)

#define EBAR() do { \
  __builtin_amdgcn_s_barrier(); \
  asm volatile("" ::: "memory"); \
} while(0)

extern "C" __global__ __launch_bounds__(256)
void k_gemm(const unsigned char* __restrict__ xq,
            const unsigned char* __restrict__ wq,
            unsigned long long* __restrict__ cpk,
            unsigned char* __restrict__ cnt8,
            float* __restrict__ out){
    __shared__ __align__(16) char As[3][8192];
    __shared__ __align__(16) char Bs[3][8192];
    __shared__ int lcnt[128];
    const int tid = threadIdx.x;

    // bijective chunked XCD remap: 6288 = 8*786
    const int orig  = blockIdx.x;
    const int newid = (orig & 7) * 786 + (orig >> 3);
    const int bm    = (newid & 15) * 128;
    const int cb    = newid >> 4;               // column block 0..392
    const int bn    = cb * 128;

    const int wv = tid >> 6, lane = tid & 63;
    const int wm = wv >> 1,  wn = wv & 1;       // 2x2 waves, 64x64 each
    const int lr = lane & 15, lk = lane >> 4;

    if (tid < 128) lcnt[tid] = 0;

    i32x4 zi4 = {0, 0, 0, 0};
    i32x4 acc[4][4];
    for (int m = 0; m < 4; ++m) for (int n = 0; n < 4; ++n) acc[m][n] = zi4;

    const size_t offA0 = (size_t)(bm + (tid & 127))*DIM + (tid >> 7)*16;
    const size_t offB0 = (size_t)(bn + (tid & 127))*DIM + (tid >> 7)*16;

    const size_t n4 = (size_t)NTOK * OUTD / 4;  // 25,731,584
    const float4 z4 = make_float4(0.f, 0.f, 0.f, 0.f);

    // ---- ring-3 pipeline over 16 K-tiles (BK=64) ----
    STAGE(0, 0);
    STAGE(1, 64);
    STAGE(2, 128); ZSTORE(0);  VBL(9);  COMPUTE(0); EBAR();
    STAGE(0, 192); ZSTORE(1);  VBL(10); COMPUTE(1); EBAR();
    {
        int bufS = 1, bufC = 2;
        for (int t = 2; t <= 13; ++t){
            STAGE(bufS, (t+2)*64);
            ZSTORE(t);
            VBL(11);
            COMPUTE(bufC);
            EBAR();
            bufS = (bufS == 2) ? 0 : bufS + 1;
            bufC = (bufC == 2) ? 0 : bufC + 1;
        }
    }
    ZSTORE(14); VBL(7); COMPUTE(2); EBAR();
    ZSTORE(15); VBL(3); COMPUTE(0);

    // epilogue: cos ~= dot/(512*512); append to (row, cb) segments
    const float inv = 1.0f / 262144.0f;
    #pragma unroll
    for (int n = 0; n < 4; ++n){
        int gcol = bn + wn*64 + n*16 + lr;
        bool ok = gcol < OUTD;
        #pragma unroll
        for (int m = 0; m < 4; ++m){
            int lr0 = wm*64 + m*16 + lk*4;        // local row (C/D layout)
            #pragma unroll
            for (int r = 0; r < 4; ++r){
                float sc = (float)acc[m][n][r] * inv;
                if (ok && sc > THRESH){
                    int lrow = lr0 + r;
                    int pos = atomicAdd(&lcnt[lrow], 1);   // LDS atomic only
                    if (pos < SEGC)
                        cpk[((size_t)(bm + lrow)*NCB + cb)*SEGC + pos] =
                            ((unsigned long long)(unsigned)gcol << 32) |
                            (unsigned long long)__float_as_uint(sc);
                }
            }
        }
    }
    __syncthreads();                 // drains cpk + trailing zero stores
    if (tid < 128)
        cnt8[(size_t)(bm + tid)*NCB + cb] =
            (unsigned char)min(lcnt[tid], SEGC);
}

// -------- kernel 4: select + f64 refine + scatter (zeroing in gemm) -------
// R22: SINGLE global scan — candidates cached in LDS (cand[768], 31 sigma
// overflow margin); histogram built same pass; bstar via parallel suffix-sum
// (replaces 256-iter serial loop); select runs from LDS.
// Determinism: cand[] is an arrival-ordered SET; refine set = {bin >= bstar}
// is a set-function of it; f64 scores + (score desc, idx asc) sort
// canonicalize -> output independent of arrival order.
extern "C" __global__ __launch_bounds__(256)
void k_sel(const float* __restrict__ x, const float* __restrict__ w,
           const float* __restrict__ bias,
           const unsigned long long* __restrict__ cpk,
           const unsigned char* __restrict__ cnt8,
           const double* __restrict__ ri64,
           float* __restrict__ out){
    const int row = blockIdx.x, tid = threadIdx.x;
    __shared__ float  xl[DIM];
    __shared__ int    hist[256];
    __shared__ unsigned long long cand[CCAP];
    __shared__ int    bstar, nref, ncand;
    __shared__ int    ridx[RCAP];
    __shared__ double rsc[RCAP];
    __shared__ double rdv[RCAP];

    ((float4*)xl)[tid] = ((const float4*)(x + (size_t)row*DIM))[tid];
    hist[tid] = 0;
    if (tid == 0){ nref = 0; ncand = 0; bstar = 0; }
    __syncthreads();

    const unsigned char* rc8 = cnt8 + (size_t)row*NCB;
    const unsigned long long* rseg = cpk + (size_t)row*NCB*SEGC;

    // single global scan: cache candidates in LDS + histogram
    // (bins of 7.8e-4 over [0.08, 0.28])
    for (int cb = tid; cb < NCB; cb += 256){
        int c = rc8[cb];
        for (int j = 0; j < c; ++j){
            unsigned long long pk = rseg[cb*SEGC + j];
            int p = atomicAdd(&ncand, 1);
            if (p < CCAP) cand[p] = pk;
            float s = __uint_as_float((unsigned)(pk & 0xFFFFFFFFu));
            int b = (int)((s - THRESH) * 1280.f);
            b = max(0, min(255, b));
            atomicAdd(&hist[b], 1);
        }
    }
    __syncthreads();

    // parallel suffix sum over hist (in place): hist[b] = sum_{i>=b} hist[i]
    for (int d = 1; d < 256; d <<= 1){
        int v = (tid + d < 256) ? hist[tid + d] : 0;
        __syncthreads();
        hist[tid] += v;
        __syncthreads();
    }
    // bstar = largest b with suffix(b) >= NREF (0 if total < NREF)
    if (hist[tid] >= NREF && (tid == 255 || hist[tid + 1] < NREF)) bstar = tid;
    __syncthreads();
    const int bs_ = bstar;

    // select from LDS cache
    const int nc = min(ncand, CCAP);
    for (int j = tid; j < nc; j += 256){
        unsigned long long pk = cand[j];
        float s = __uint_as_float((unsigned)(pk & 0xFFFFFFFFu));
        int b = (int)((s - THRESH) * 1280.f);
        b = max(0, min(255, b));
        if (b >= bs_){
            int p = atomicAdd(&nref, 1);
            if (p < RCAP) ridx[p] = (int)(pk >> 32);
        }
    }
    __syncthreads();
    const int nr = min(nref, RCAP);

    // f64 refine: one wave per candidate, float4-vectorized loads
    const int wv = tid >> 6, lane = tid & 63;
    const float4* xl4 = (const float4*)xl;
    for (int q = wv; q < nr; q += 4){
        int col = ridx[q];
        const float4* wr4 = (const float4*)(w + (size_t)col*DIM);
        double s = 0.0;
        #pragma unroll
        for (int u = 0; u < 4; ++u){
            float4 a = xl4[lane + 64*u];
            float4 b = wr4[lane + 64*u];
            s = fma((double)a.x, (double)b.x, s);
            s = fma((double)a.y, (double)b.y, s);
            s = fma((double)a.z, (double)b.z, s);
            s = fma((double)a.w, (double)b.w, s);
        }
        for (int d = 32; d >= 1; d >>= 1) s += __shfl_xor(s, d, 64);
        if (lane == 0){ rdv[q] = s; rsc[q] = s * ri64[col]; }
    }
    __syncthreads();
    if (tid >= nr){ rsc[tid] = -1.0e300; ridx[tid] = 0x7FFFFFFF; rdv[tid] = 0.0; }
    __syncthreads();

    // bitonic sort 256: descending score, ties -> smaller index
    for (int k = 2; k <= RCAP; k <<= 1){
        for (int j = k >> 1; j > 0; j >>= 1){
            int i = tid, ixj = i ^ j;
            if (ixj > i){
                double sa = rsc[i], sb = rsc[ixj];
                int ia = ridx[i], ib = ridx[ixj];
                bool dir = ((i & k) == 0);
                bool pb = (sb > sa) || (sb == sa && ib < ia);
                if (pb == dir){
                    rsc[i] = sb; rsc[ixj] = sa;
                    ridx[i] = ib; ridx[ixj] = ia;
                    double t = rdv[i]; rdv[i] = rdv[ixj]; rdv[ixj] = t;
                }
            }
            __syncthreads();
        }
    }
    if (tid < TOPK && tid < nr){
        int col = ridx[tid];
        out[(size_t)row*OUTD + col] = (float)rdv[tid] + bias[col];
    }
}

// ---------------- launch --------------------------------------------------
extern "C" void kernel_launch(void* const* d_in, const int* in_sizes, int n_in,
                              void* d_out, int out_size, void* d_ws, size_t ws_size,
                              hipStream_t stream){
    const float* x    = (const float*)d_in[0];
    const float* wgt  = (const float*)d_in[1];
    const float* bias = (const float*)d_in[2];
    float* out = (float*)d_out;
    char* ws = (char*)d_ws;

    // workspace carve (~132 MB)
    unsigned char* wq = (unsigned char*)ws;                         // 51,511,296
    unsigned char* xq = (unsigned char*)(ws + 51511296);            //  2,097,152
    double* ri64 = (double*)(ws + 53608448);                        //    402,432
    unsigned long long* cpk = (unsigned long long*)(ws + 54010880); // 77,266,944
    unsigned char* cnt8 = (unsigned char*)(ws + 131277824);         //    804,864

    k_init <<<NTOK/4, 256, 0, stream>>>(x, xq);
    k_wnorm<<<OPAD/4, 256, 0, stream>>>(wgt, wq, ri64);
    k_gemm <<<NBLK, 256, 0, stream>>>(xq, wq, cpk, cnt8, out);
    k_sel  <<<NTOK, 256, 0, stream>>>(x, wgt, bias, cpk, cnt8, ri64, out);
}